// Round 2
// baseline (1110.008 us; speedup 1.0000x reference)
//
#include <hip/hip_runtime.h>

#define DEV static __device__ __forceinline__

typedef short bf16x8 __attribute__((ext_vector_type(8)));
typedef float floatx4 __attribute__((ext_vector_type(4)));
typedef unsigned short ushort4v __attribute__((ext_vector_type(4)));
typedef unsigned short ushort8v __attribute__((ext_vector_type(8)));

DEV unsigned short f32_bf16(float f) {
  unsigned int u = __builtin_bit_cast(unsigned int, f);
  u = u + 0x7fffu + ((u >> 16) & 1u);
  return (unsigned short)(u >> 16);
}
DEV float bf2f(unsigned short u) {
  unsigned int v = ((unsigned int)u) << 16;
  return __builtin_bit_cast(float, v);
}
DEV float sigmoidf_(float x) { return 1.0f / (1.0f + __expf(-x)); }
DEV float siluf_(float x) { return x * sigmoidf_(x); }

// ---------------------------------------------------------------------------
// bf16 MFMA GEMM:  C[M,N] = A[M,K] @ B[N,K]^T.
// MODE 0: store fp32. MODE 1: store bf16. MODE 2: store bf16(silu(acc)*other).
// Block = 4 waves; wave tile (WM*16)x64; block tile (WM*64)x64.
// ---------------------------------------------------------------------------
template <int WM, int MODE>
__global__ __launch_bounds__(256) void gemm_bf16_nt(
    const unsigned short* __restrict__ A, const unsigned short* __restrict__ B,
    void* __restrict__ Cv, const unsigned short* __restrict__ other,
    int M, int N, int K, int lda, int ldb, int ldc,
    long long bsA, long long bsB, long long bsC) {
  A += (long long)blockIdx.z * bsA;
  B += (long long)blockIdx.z * bsB;
  const long long coff = (long long)blockIdx.z * bsC;
  const int w = threadIdx.x >> 6;
  const int lane = threadIdx.x & 63;
  const int lm = lane & 15;
  const int ko = (lane >> 4) << 3;
  const int bn0 = blockIdx.x << 6;
  const int m_base = blockIdx.y * (WM * 64) + w * (WM * 16);

  const unsigned short* arow[WM];
#pragma unroll
  for (int i = 0; i < WM; ++i)
    arow[i] = A + (long long)(m_base + i * 16 + lm) * lda + ko;

  int nv = (N - bn0) >> 4;
  nv = nv > 4 ? 4 : nv;
  const unsigned short* brow[4];
#pragma unroll
  for (int j = 0; j < 4; ++j) {
    int nr = bn0 + j * 16 + lm;
    brow[j] = B + (long long)(j < nv ? nr : 0) * ldb + ko;
  }

  floatx4 acc[WM][4];
#pragma unroll
  for (int i = 0; i < WM; ++i)
#pragma unroll
    for (int j = 0; j < 4; ++j) acc[i][j] = (floatx4){0.f, 0.f, 0.f, 0.f};

  if (nv == 4) {
    for (int k0 = 0; k0 < K; k0 += 32) {
      bf16x8 a[WM], b[4];
#pragma unroll
      for (int i = 0; i < WM; ++i) a[i] = *(const bf16x8*)(arow[i] + k0);
#pragma unroll
      for (int j = 0; j < 4; ++j) b[j] = *(const bf16x8*)(brow[j] + k0);
#pragma unroll
      for (int i = 0; i < WM; ++i)
#pragma unroll
        for (int j = 0; j < 4; ++j)
          acc[i][j] = __builtin_amdgcn_mfma_f32_16x16x32_bf16(a[i], b[j], acc[i][j], 0, 0, 0);
    }
  } else {
    for (int k0 = 0; k0 < K; k0 += 32) {
      bf16x8 a[WM];
#pragma unroll
      for (int i = 0; i < WM; ++i) a[i] = *(const bf16x8*)(arow[i] + k0);
#pragma unroll
      for (int j = 0; j < 4; ++j) {
        if (j < nv) {
          bf16x8 b = *(const bf16x8*)(brow[j] + k0);
#pragma unroll
          for (int i = 0; i < WM; ++i)
            acc[i][j] = __builtin_amdgcn_mfma_f32_16x16x32_bf16(a[i], b, acc[i][j], 0, 0, 0);
        }
      }
    }
  }

  const int r0 = (lane >> 4) << 2;
#pragma unroll
  for (int i = 0; i < WM; ++i) {
#pragma unroll
    for (int j = 0; j < 4; ++j) {
      if (j < nv) {
        int col = bn0 + j * 16 + lm;
        long long base = (long long)(m_base + i * 16 + r0) * ldc + col;
#pragma unroll
        for (int r = 0; r < 4; ++r) {
          long long idx = base + (long long)r * ldc;
          float v = acc[i][j][r];
          if constexpr (MODE == 0) {
            ((float*)Cv)[coff + idx] = v;
          } else if constexpr (MODE == 1) {
            ((unsigned short*)Cv)[coff + idx] = f32_bf16(v);
          } else {
            float u = bf2f(other[coff + idx]);
            ((unsigned short*)Cv)[coff + idx] = f32_bf16(siluf_(v) * u);
          }
        }
      }
    }
  }
}

// ---------------------------------------------------------------------------
__global__ __launch_bounds__(256) void f32_to_bf16_k(const float* __restrict__ src,
                                                     unsigned short* __restrict__ dst,
                                                     long long n4) {
  long long i = (long long)blockIdx.x * 256 + threadIdx.x;
  if (i < n4) {
    float4 v = ((const float4*)src)[i];
    ushort4v o = {f32_bf16(v.x), f32_bf16(v.y), f32_bf16(v.z), f32_bf16(v.w)};
    ((ushort4v*)dst)[i] = o;
  }
}

__global__ __launch_bounds__(256) void zero_out_k(float* __restrict__ o, long long n) {
  long long i = (long long)blockIdx.x * 256 + threadIdx.x;
  if (i < n) o[i] = 0.f;
}

// ---------------------------------------------------------------------------
// RMSNorm over 1024 cols (fp32 in) -> bf16
// ---------------------------------------------------------------------------
__global__ __launch_bounds__(256) void rmsnorm1024_bf16_k(const float* __restrict__ x,
                                                          const float* __restrict__ w,
                                                          unsigned short* __restrict__ out,
                                                          float eps) {
  long long row = blockIdx.x;
  int t = threadIdx.x;
  float4 v = ((const float4*)(x + row * 1024))[t];
  float ss = v.x * v.x + v.y * v.y + v.z * v.z + v.w * v.w;
  __shared__ float red[4];
#pragma unroll
  for (int o = 32; o > 0; o >>= 1) ss += __shfl_down(ss, o, 64);
  if ((t & 63) == 0) red[t >> 6] = ss;
  __syncthreads();
  float tot = red[0] + red[1] + red[2] + red[3];
  float sc = rsqrtf(tot * (1.0f / 1024.0f) + eps);
  float4 wv = ((const float4*)w)[t];
  ushort4v o = {f32_bf16(v.x * sc * wv.x), f32_bf16(v.y * sc * wv.y),
                f32_bf16(v.z * sc * wv.z), f32_bf16(v.w * sc * wv.w)};
  ((ushort4v*)(out + row * 1024))[t] = o;
}

// ---------------------------------------------------------------------------
// Gated RMSNorm, 2048 cols: g = y(bf16) * silu(z fp32); out bf16
// ---------------------------------------------------------------------------
__global__ __launch_bounds__(256) void gated_rmsnorm2048_k(const unsigned short* __restrict__ y,
                                                           const float* __restrict__ z,
                                                           const float* __restrict__ w,
                                                           unsigned short* __restrict__ out,
                                                           float eps) {
  long long row = blockIdx.x;
  int t = threadIdx.x;
  ushort8v yv = ((const ushort8v*)(y + row * 2048))[t];
  float zz[8];
  *(float4*)&zz[0] = ((const float4*)(z + row * 2048))[2 * t];
  *(float4*)&zz[4] = ((const float4*)(z + row * 2048))[2 * t + 1];
  float g[8];
  float ss = 0.f;
#pragma unroll
  for (int j = 0; j < 8; ++j) {
    g[j] = bf2f(yv[j]) * siluf_(zz[j]);
    ss += g[j] * g[j];
  }
  __shared__ float red[4];
#pragma unroll
  for (int o = 32; o > 0; o >>= 1) ss += __shfl_down(ss, o, 64);
  if ((t & 63) == 0) red[t >> 6] = ss;
  __syncthreads();
  float tot = red[0] + red[1] + red[2] + red[3];
  float sc = rsqrtf(tot * (1.0f / 2048.0f) + eps);
  float ww[8];
  *(float4*)&ww[0] = ((const float4*)w)[2 * t];
  *(float4*)&ww[4] = ((const float4*)w)[2 * t + 1];
  ushort8v o;
#pragma unroll
  for (int j = 0; j < 8; ++j) o[j] = f32_bf16(g[j] * sc * ww[j]);
  ((ushort8v*)(out + row * 2048))[t] = o;
}

// ---------------------------------------------------------------------------
// Causal depthwise conv (K=4) + bias + silu: xraw fp32 [M,2304] -> xBC bf16 [M,2304]
// ---------------------------------------------------------------------------
__global__ __launch_bounds__(256) void conv_silu_k(const float* __restrict__ xraw,
                                                   const float* __restrict__ wconv,
                                                   const float* __restrict__ bconv,
                                                   unsigned short* __restrict__ xBC) {
  int m = blockIdx.x;
  int l = m & 2047;
  for (int ch = threadIdx.x; ch < 2304; ch += 256) {
    float acc = bconv[ch];
#pragma unroll
    for (int k = 0; k < 4; ++k) {
      int lk = l + k - 3;
      if (lk >= 0) acc += xraw[(long long)(m + k - 3) * 2304 + ch] * wconv[ch * 4 + k];
    }
    xBC[(long long)m * 2304 + ch] = f32_bf16(siluf_(acc));
  }
}

// ---------------------------------------------------------------------------
// dt = softplus(dtraw + dt_bias)
// ---------------------------------------------------------------------------
__global__ __launch_bounds__(256) void dt_softplus_k(const float* __restrict__ dtraw,
                                                     const float* __restrict__ dt_bias,
                                                     float* __restrict__ dt_s) {
  int i = blockIdx.x * 256 + threadIdx.x;  // < 4096*32
  float xv = dtraw[i] + dt_bias[i & 31];
  dt_s[i] = xv > 20.f ? xv : log1pf(expf(xv));
}

// ---------------------------------------------------------------------------
// dA_cs[(b*32+h)*16+c][q] = cumsum_q( dt_s[b,c*128+q,h] * (-exp(A_log[h])) )
// ---------------------------------------------------------------------------
__global__ __launch_bounds__(128) void dA_cumsum_k(const float* __restrict__ dt_s,
                                                   const float* __restrict__ A_log,
                                                   float* __restrict__ dA_cs) {
  int bi = blockIdx.x;
  int c = bi & 15, h = (bi >> 4) & 31, b = bi >> 9;
  int q = threadIdx.x;
  float A = -expf(A_log[h]);
  float v = dt_s[((long long)(b * 2048 + c * 128 + q)) * 32 + h] * A;
  __shared__ float sbuf[128];
  sbuf[q] = v;
  __syncthreads();
  for (int off = 1; off < 128; off <<= 1) {
    float tv = (q >= off) ? sbuf[q - off] : 0.f;
    __syncthreads();
    sbuf[q] += tv;
    __syncthreads();
  }
  dA_cs[(long long)bi * 128 + q] = sbuf[q];
}

// ---------------------------------------------------------------------------
// S3: Y_diag (-> y bf16) and per-chunk local states (-> states bf16)
// blockIdx.x = b*512 + c*32 + h
// ---------------------------------------------------------------------------
__global__ __launch_bounds__(256) void ssd_diag_states_k(
    const unsigned short* __restrict__ xBC, const float* __restrict__ dt_s,
    const float* __restrict__ dA_cs, const float* __restrict__ G,
    unsigned short* __restrict__ y, unsigned short* __restrict__ states) {
  const int bx = blockIdx.x;
  const int h = bx & 31, c = (bx >> 5) & 15, b = bx >> 9;
  const int t = threadIdx.x;
  __shared__ float xd[128][68];
  __shared__ float Acs[128];
  __shared__ float wdec[128];
  __shared__ float Bst[32][132];
  const long long rowbase = (long long)b * 2048 + c * 128;
  const long long abase = ((long long)((b * 32 + h) * 16 + c)) << 7;
  {
    int s = t >> 1, half = t & 1;
    long long m = rowbase + s;
    float dtv = dt_s[m * 32 + h];
    const ushort8v* xv = (const ushort8v*)(xBC + m * 2304 + h * 64 + half * 32);
    float* dst = &xd[s][half * 32];
#pragma unroll
    for (int i = 0; i < 4; ++i) {
      ushort8v vv = xv[i];
#pragma unroll
      for (int j = 0; j < 8; ++j) dst[i * 8 + j] = bf2f(vv[j]) * dtv;
    }
  }
  if (t < 128) {
    float a = dA_cs[abase + t];
    Acs[t] = a;
    wdec[t] = __expf(dA_cs[abase + 127] - a);
  }
  __syncthreads();
  // ---- Y_diag ----
  {
    int q = t >> 1, ph = t & 1;
    float aq = Acs[q];
    const float* Grow = G + (((long long)(b * 16 + c)) * 128 + q) * 128;
    float accd[32];
#pragma unroll
    for (int p = 0; p < 32; ++p) accd[p] = 0.f;
    for (int s = 0; s <= q; ++s) {
      float wgt = Grow[s] * __expf(aq - Acs[s]);
      const float* xr = &xd[s][ph * 32];
#pragma unroll
      for (int p = 0; p < 32; ++p) accd[p] += wgt * xr[p];
    }
    unsigned short* yo = y + (rowbase + q) * 2048 + h * 64 + ph * 32;
#pragma unroll
    for (int i = 0; i < 4; ++i) {
      ushort8v o;
#pragma unroll
      for (int j = 0; j < 8; ++j) o[j] = f32_bf16(accd[i * 8 + j]);
      ((ushort8v*)yo)[i] = o;
    }
  }
  // ---- local states ----
  {
    int n = t & 127, phh = t >> 7;
    float accs[32];
#pragma unroll
    for (int p = 0; p < 32; ++p) accs[p] = 0.f;
    for (int sc = 0; sc < 4; ++sc) {
      __syncthreads();
      {
        int sl = t >> 3, vv = t & 7;
        long long m = rowbase + sc * 32 + sl;
        const ushort8v* src = (const ushort8v*)(xBC + m * 2304 + 2048 + vv * 16);
        float* dst = &Bst[sl][vv * 16];
#pragma unroll
        for (int i = 0; i < 2; ++i) {
          ushort8v u = src[i];
#pragma unroll
          for (int j = 0; j < 8; ++j) dst[i * 8 + j] = bf2f(u[j]);
        }
      }
      __syncthreads();
      for (int sl = 0; sl < 32; ++sl) {
        int s = sc * 32 + sl;
        float bv = Bst[sl][n] * wdec[s];
        const float* xr = &xd[s][phh * 32];
#pragma unroll
        for (int p = 0; p < 32; ++p) accs[p] += bv * xr[p];
      }
    }
    unsigned short* st = states + (long long)bx * 8192;
#pragma unroll
    for (int p = 0; p < 32; ++p) st[(long long)(phh * 32 + p) * 128 + n] = f32_bf16(accs[p]);
  }
}

// ---------------------------------------------------------------------------
// S4: inter-chunk scan in place (states bf16, carry fp32)
// ---------------------------------------------------------------------------
__global__ __launch_bounds__(256) void ssd_scan_k(const float* __restrict__ dA_cs,
                                                  unsigned short* __restrict__ states) {
  int h = blockIdx.x & 31, b = blockIdx.x >> 5;
  int t = threadIdx.x;
  float carry[32];
#pragma unroll
  for (int i = 0; i < 32; ++i) carry[i] = 0.f;
  for (int c = 0; c < 16; ++c) {
    long long base = ((long long)((b * 16 + c) * 32 + h)) * 8192;
    float dec = __expf(dA_cs[(((long long)((b * 32 + h) * 16 + c)) << 7) + 127]);
#pragma unroll
    for (int i = 0; i < 32; ++i) {
      long long idx = base + t + i * 256;
      float local = bf2f(states[idx]);
      states[idx] = f32_bf16(carry[i]);
      carry[i] = dec * carry[i] + local;
    }
  }
}

// ---------------------------------------------------------------------------
// S5: y += exp(Acs[q]) * C[q,:] @ state^T + D[h]*x   (y bf16 RMW)
// ---------------------------------------------------------------------------
__global__ __launch_bounds__(256) void ssd_off_k(const unsigned short* __restrict__ xBC,
                                                 const float* __restrict__ dA_cs,
                                                 const unsigned short* __restrict__ states,
                                                 const float* __restrict__ Dvec,
                                                 unsigned short* __restrict__ y) {
  const int bx = blockIdx.x;
  const int h = bx & 31, c = (bx >> 5) & 15, b = bx >> 9;
  const int t = threadIdx.x;
  __shared__ float S[128][65];  // S[n][p]
  __shared__ float eA[128];
  const long long rowbase = (long long)b * 2048 + c * 128;
  const long long abase = ((long long)((b * 32 + h) * 16 + c)) << 7;
  {
    const unsigned short* st = states + (long long)bx * 8192;
    int p = t >> 2, n0 = (t & 3) * 32;
#pragma unroll
    for (int i = 0; i < 32; i += 8) {
      ushort8v v = *(const ushort8v*)(st + (long long)p * 128 + n0 + i);
#pragma unroll
      for (int j = 0; j < 8; ++j) S[n0 + i + j][p] = bf2f(v[j]);
    }
  }
  if (t < 128) eA[t] = __expf(dA_cs[abase + t]);
  __syncthreads();
  int q = t >> 1, ph = t & 1;
  float acc[32];
#pragma unroll
  for (int p = 0; p < 32; ++p) acc[p] = 0.f;
  const unsigned short* Crow = xBC + (rowbase + q) * 2304 + 2176;
  for (int n = 0; n < 128; ++n) {
    float cv = bf2f(Crow[n]);
    const float* sr = &S[n][ph * 32];
#pragma unroll
    for (int p = 0; p < 32; ++p) acc[p] += cv * sr[p];
  }
  float e = eA[q];
  float Dh = Dvec[h];
  const ushort8v* xr = (const ushort8v*)(xBC + (rowbase + q) * 2304 + h * 64 + ph * 32);
  ushort8v* yr = (ushort8v*)(y + (rowbase + q) * 2048 + h * 64 + ph * 32);
#pragma unroll
  for (int i = 0; i < 4; ++i) {
    ushort8v yv = yr[i];
    ushort8v xv = xr[i];
    ushort8v o;
#pragma unroll
    for (int j = 0; j < 8; ++j) {
      float v = bf2f(yv[j]) + e * acc[i * 8 + j] + Dh * bf2f(xv[j]);
      o[j] = f32_bf16(v);
    }
    yr[i] = o;
  }
}

// ---------------------------------------------------------------------------
__global__ __launch_bounds__(256) void add_f32_k(const float* __restrict__ a,
                                                 const float* __restrict__ b,
                                                 float* __restrict__ o, long long n4) {
  long long i = (long long)blockIdx.x * 256 + threadIdx.x;
  if (i < n4) {
    float4 x = ((const float4*)a)[i];
    float4 yv = ((const float4*)b)[i];
    ((float4*)o)[i] = make_float4(x.x + yv.x, x.y + yv.y, x.z + yv.z, x.w + yv.w);
  }
}

// ---------------------------------------------------------------------------
extern "C" void kernel_launch(void* const* d_in, const int* in_sizes, int n_in, void* d_out,
                              int out_size, void* d_ws, size_t ws_size, hipStream_t stream) {
  const float* hs = (const float*)d_in[0];
  const float* w_ln1 = (const float*)d_in[1];
  const float* w_in = (const float*)d_in[2];
  const float* w_conv = (const float*)d_in[3];
  const float* b_conv = (const float*)d_in[4];
  const float* dt_bias = (const float*)d_in[5];
  const float* A_log = (const float*)d_in[6];
  const float* Dvec = (const float*)d_in[7];
  const float* w_mnorm = (const float*)d_in[8];
  const float* w_out = (const float*)d_in[9];
  const float* w_ln2 = (const float*)d_in[10];
  const float* w_gate = (const float*)d_in[11];
  const float* w_up = (const float*)d_in[12];
  const float* w_down = (const float*)d_in[13];
  float* out = (float*)d_out;
  const int M = 4096;

  // ---- arena layout (bytes). Peak-phase aliasing; total = 133,234,688 B.
  char* ws = (char*)d_ws;
  const size_t R0 = 0;                      // 33,554,432: z fp32 [s3..s11] -> act bf16 [s16..s17]
  const size_t R1 = 33554432;               // 37,748,736: xraw fp32 [s3..s4] -> states bf16 + y bf16
                                            //   [s8..s11] -> outtmp fp32 [s12..s13] -> upo bf16
                                            //   [s15..s16] -> downtmp fp32 [s17..s18]
  const size_t R1b = R1 + 33554432;         // 4,194,304 slack: wbf_out [s5..s12]
  const size_t R2 = 71303168;               // 18,874,368: xBC bf16 [s4..s10] -> ygn bf16 [s11..s12]
                                            //   -> h2 bf16 [s14..s16]
  const size_t R3 = 90177536;               // 17,367,040: hnorm+wbf_in [s1..s3] -> dt_s/dA/G
                                            //   [s5..s10] -> mamba_hidden fp32 [s13..s18]
  const size_t R4 = 107544576;              // 524,288: dtraw fp32 [s3..s5]
  const size_t W0 = 108068864;              // 25,165,824: wbf_gate | wbf_up | wbf_down
  const size_t NEED = 133234688;

  if (ws_size < NEED) {  // constant per-session: graph-capture-safe
    hipLaunchKernelGGL(zero_out_k, dim3((out_size + 255) / 256), dim3(256), 0, stream, out,
                       (long long)out_size);
    return;
  }

  float* z = (float*)(ws + R0);
  unsigned short* act = (unsigned short*)(ws + R0);
  float* xraw = (float*)(ws + R1);
  unsigned short* states = (unsigned short*)(ws + R1);
  unsigned short* ybuf = (unsigned short*)(ws + R1 + 16777216);
  float* outtmp = (float*)(ws + R1);
  unsigned short* upo = (unsigned short*)(ws + R1);
  float* downtmp = (float*)(ws + R1);
  unsigned short* wbf_out = (unsigned short*)(ws + R1b);
  unsigned short* xBC = (unsigned short*)(ws + R2);
  unsigned short* ygn = (unsigned short*)(ws + R2);
  unsigned short* h2 = (unsigned short*)(ws + R2);
  unsigned short* hnorm = (unsigned short*)(ws + R3);
  unsigned short* wbf_in = (unsigned short*)(ws + R3 + 8388608);
  float* dt_s = (float*)(ws + R3);
  float* dA_cs = (float*)(ws + R3 + 524288);
  float* Gbuf = (float*)(ws + R3 + 1048576);
  float* mh = (float*)(ws + R3);
  float* dtraw = (float*)(ws + R4);
  unsigned short* wbf_gate = (unsigned short*)(ws + W0);
  unsigned short* wbf_up = (unsigned short*)(ws + W0 + 8388608);
  unsigned short* wbf_down = (unsigned short*)(ws + W0 + 16777216);

  // s1: rmsnorm(ln1) -> hnorm bf16
  hipLaunchKernelGGL(rmsnorm1024_bf16_k, dim3(M), dim3(256), 0, stream, hs, w_ln1, hnorm, 1e-6f);
  // s2: weight conversions (w_out deferred past xraw's lifetime)
  hipLaunchKernelGGL(f32_to_bf16_k, dim3(4384), dim3(256), 0, stream, w_in, wbf_in, 1122304LL);
  hipLaunchKernelGGL(f32_to_bf16_k, dim3(4096), dim3(256), 0, stream, w_gate, wbf_gate, 1048576LL);
  hipLaunchKernelGGL(f32_to_bf16_k, dim3(4096), dim3(256), 0, stream, w_up, wbf_up, 1048576LL);
  hipLaunchKernelGGL(f32_to_bf16_k, dim3(4096), dim3(256), 0, stream, w_down, wbf_down, 1048576LL);
  // s3: in_proj, split into z / xBC-raw / dt-raw
  hipLaunchKernelGGL((gemm_bf16_nt<4, 0>), dim3(32, 16, 1), dim3(256), 0, stream, hnorm, wbf_in,
                     (void*)z, (const unsigned short*)nullptr, M, 2048, 1024, 1024, 1024, 2048,
                     0LL, 0LL, 0LL);
  hipLaunchKernelGGL((gemm_bf16_nt<4, 0>), dim3(36, 16, 1), dim3(256), 0, stream, hnorm,
                     wbf_in + 2048 * 1024, (void*)xraw, (const unsigned short*)nullptr, M, 2304,
                     1024, 1024, 1024, 2304, 0LL, 0LL, 0LL);
  hipLaunchKernelGGL((gemm_bf16_nt<4, 0>), dim3(1, 16, 1), dim3(256), 0, stream, hnorm,
                     wbf_in + 4352 * 1024, (void*)dtraw, (const unsigned short*)nullptr, M, 32,
                     1024, 1024, 1024, 32, 0LL, 0LL, 0LL);
  // s4: conv + silu -> xBC bf16
  hipLaunchKernelGGL(conv_silu_k, dim3(M), dim3(256), 0, stream, xraw, w_conv, b_conv, xBC);
  // s4b: convert w_out now (xraw dead)
  hipLaunchKernelGGL(f32_to_bf16_k, dim3(2048), dim3(256), 0, stream, w_out, wbf_out, 524288LL);
  // s5: dt softplus
  hipLaunchKernelGGL(dt_softplus_k, dim3(512), dim3(256), 0, stream, dtraw, dt_bias, dt_s);
  // s6: dA cumsum
  hipLaunchKernelGGL(dA_cumsum_k, dim3(1024), dim3(128), 0, stream, dt_s, A_log, dA_cs);
  // s7: G = C @ B^T per chunk (reads bf16 xBC directly)
  hipLaunchKernelGGL((gemm_bf16_nt<2, 0>), dim3(2, 1, 32), dim3(256), 0, stream, xBC + 2176,
                     xBC + 2048, (void*)Gbuf, (const unsigned short*)nullptr, 128, 128, 128, 2304,
                     2304, 128, 294912LL, 294912LL, 16384LL);
  // s8: Y_diag + local states
  hipLaunchKernelGGL(ssd_diag_states_k, dim3(1024), dim3(256), 0, stream, xBC, dt_s, dA_cs, Gbuf,
                     ybuf, states);
  // s9: inter-chunk scan
  hipLaunchKernelGGL(ssd_scan_k, dim3(64), dim3(256), 0, stream, dA_cs, states);
  // s10: Y_off + D-skip
  hipLaunchKernelGGL(ssd_off_k, dim3(1024), dim3(256), 0, stream, xBC, dA_cs, states, Dvec, ybuf);
  // s11: gated rmsnorm -> ygn bf16
  hipLaunchKernelGGL(gated_rmsnorm2048_k, dim3(M), dim3(256), 0, stream, ybuf, z, w_mnorm, ygn,
                     1e-5f);
  // s12: out_proj -> outtmp fp32
  hipLaunchKernelGGL((gemm_bf16_nt<4, 0>), dim3(16, 16, 1), dim3(256), 0, stream, ygn, wbf_out,
                     (void*)outtmp, (const unsigned short*)nullptr, M, 1024, 2048, 2048, 2048,
                     1024, 0LL, 0LL, 0LL);
  // s13: residual add -> mh
  hipLaunchKernelGGL(add_f32_k, dim3(4096), dim3(256), 0, stream, hs, outtmp, mh, 1048576LL);
  // s14: rmsnorm(ln2) -> h2 bf16
  hipLaunchKernelGGL(rmsnorm1024_bf16_k, dim3(M), dim3(256), 0, stream, mh, w_ln2, h2, 1e-6f);
  // s15: up -> upo bf16
  hipLaunchKernelGGL((gemm_bf16_nt<4, 1>), dim3(64, 16, 1), dim3(256), 0, stream, h2, wbf_up,
                     (void*)upo, (const unsigned short*)nullptr, M, 4096, 1024, 1024, 1024, 4096,
                     0LL, 0LL, 0LL);
  // s16: gate with fused swiglu epilogue -> act bf16
  hipLaunchKernelGGL((gemm_bf16_nt<4, 2>), dim3(64, 16, 1), dim3(256), 0, stream, h2, wbf_gate,
                     (void*)act, upo, M, 4096, 1024, 1024, 1024, 4096, 0LL, 0LL, 0LL);
  // s17: down -> downtmp fp32
  hipLaunchKernelGGL((gemm_bf16_nt<4, 0>), dim3(16, 16, 1), dim3(256), 0, stream, act, wbf_down,
                     (void*)downtmp, (const unsigned short*)nullptr, M, 1024, 4096, 4096, 4096,
                     1024, 0LL, 0LL, 0LL);
  // s18: final residual add -> out
  hipLaunchKernelGGL(add_f32_k, dim3(4096), dim3(256), 0, stream, mh, downtmp, out, 1048576LL);
}

// Round 3
// 816.017 us; speedup vs baseline: 1.3603x; 1.3603x over previous
//
#include <hip/hip_runtime.h>

#define DEV static __device__ __forceinline__

typedef short bf16x8 __attribute__((ext_vector_type(8)));
typedef float floatx4 __attribute__((ext_vector_type(4)));
typedef unsigned short ushort4v __attribute__((ext_vector_type(4)));
typedef unsigned short ushort8v __attribute__((ext_vector_type(8)));

DEV unsigned short f32_bf16(float f) {
  unsigned int u = __builtin_bit_cast(unsigned int, f);
  u = u + 0x7fffu + ((u >> 16) & 1u);
  return (unsigned short)(u >> 16);
}
DEV float bf2f(unsigned short u) {
  unsigned int v = ((unsigned int)u) << 16;
  return __builtin_bit_cast(float, v);
}
DEV float sigmoidf_(float x) { return 1.0f / (1.0f + __expf(-x)); }
DEV float siluf_(float x) { return x * sigmoidf_(x); }

#define GLD_LDS16(g, l)                                                              \
  __builtin_amdgcn_global_load_lds((const __attribute__((address_space(1))) void*)(g), \
                                   (__attribute__((address_space(3))) void*)(l), 16, 0, 0)

// ---------------------------------------------------------------------------
// m97-style MFMA GEMM: C[M,N] = A[M,K] @ B[N,K]^T, bf16 in, 128x128 block tile,
// BK=32, LDS staging via global_load_lds(16B), XOR-swizzled k-chunks.
// Grid: (N/128, M/128, batch). MODE 0: fp32 store. 1: bf16. 2: bf16(silu(acc)*other).
// ---------------------------------------------------------------------------
template <int MODE>
__global__ __launch_bounds__(256) void gemm128(
    const unsigned short* __restrict__ A, const unsigned short* __restrict__ B,
    void* __restrict__ Cv, const unsigned short* __restrict__ other,
    int K, int lda, int ldb, int ldc, long long bsA, long long bsB, long long bsC) {
  __shared__ unsigned short As[128 * 32];
  __shared__ unsigned short Bs[128 * 32];
  A += (long long)blockIdx.z * bsA;
  B += (long long)blockIdx.z * bsB;
  const long long coff = (long long)blockIdx.z * bsC;
  const int tid = threadIdx.x;
  const int w = tid >> 6, lane = tid & 63;
  const int m0 = blockIdx.y << 7, n0 = blockIdx.x << 7;

  // staging: wave w stages rows [w*32, w*32+32) of each tile; lane l covers
  // row j*16 + (l>>2), 16B chunk (l&3), sourcing global chunk (l&3)^((l>>2)&3).
  const int srow = lane >> 2;
  const int schunk = ((lane & 3) ^ (srow & 3)) * 8;
  const unsigned short* ag0 = A + (long long)(m0 + w * 32 + srow) * lda + schunk;
  const unsigned short* ag1 = ag0 + (long long)16 * lda;
  const unsigned short* bg0 = B + (long long)(n0 + w * 32 + srow) * ldb + schunk;
  const unsigned short* bg1 = bg0 + (long long)16 * ldb;
  unsigned short* al0 = As + (w * 32) * 32 + lane * 8;
  unsigned short* al1 = As + (w * 32 + 16) * 32 + lane * 8;
  unsigned short* bl0 = Bs + (w * 32) * 32 + lane * 8;
  unsigned short* bl1 = Bs + (w * 32 + 16) * 32 + lane * 8;

  // fragments: wave (wr,wc) covers rows wr*64.., cols wc*64..
  const int wr = (w >> 1) << 6, wc = (w & 1) << 6;
  const int fr = lane & 15;
  const int slot = (((lane >> 4) ^ (fr & 3))) << 3;  // swizzled k-chunk * 8

  floatx4 acc[4][4];
#pragma unroll
  for (int i = 0; i < 4; ++i)
#pragma unroll
    for (int j = 0; j < 4; ++j) acc[i][j] = (floatx4){0.f, 0.f, 0.f, 0.f};

  for (int k0 = 0; k0 < K; k0 += 32) {
    __syncthreads();
    GLD_LDS16(ag0 + k0, al0);
    GLD_LDS16(ag1 + k0, al1);
    GLD_LDS16(bg0 + k0, bl0);
    GLD_LDS16(bg1 + k0, bl1);
    __syncthreads();
    bf16x8 af[4], bf_[4];
#pragma unroll
    for (int i = 0; i < 4; ++i)
      af[i] = *(const bf16x8*)(As + (wr + i * 16 + fr) * 32 + slot);
#pragma unroll
    for (int j = 0; j < 4; ++j)
      bf_[j] = *(const bf16x8*)(Bs + (wc + j * 16 + fr) * 32 + slot);
#pragma unroll
    for (int i = 0; i < 4; ++i)
#pragma unroll
      for (int j = 0; j < 4; ++j)
        acc[i][j] = __builtin_amdgcn_mfma_f32_16x16x32_bf16(af[i], bf_[j], acc[i][j], 0, 0, 0);
  }

  const int r0 = (lane >> 4) << 2;
#pragma unroll
  for (int i = 0; i < 4; ++i) {
#pragma unroll
    for (int j = 0; j < 4; ++j) {
      long long base = (long long)(m0 + wr + i * 16 + r0) * ldc + (n0 + wc + j * 16 + fr);
#pragma unroll
      for (int r = 0; r < 4; ++r) {
        long long idx = coff + base + (long long)r * ldc;
        float v = acc[i][j][r];
        if constexpr (MODE == 0) {
          ((float*)Cv)[idx] = v;
        } else if constexpr (MODE == 1) {
          ((unsigned short*)Cv)[idx] = f32_bf16(v);
        } else {
          ((unsigned short*)Cv)[idx] = f32_bf16(siluf_(v) * bf2f(other[idx]));
        }
      }
    }
  }
}

// ---------------------------------------------------------------------------
// small GEMM (direct-from-global), used only for the N=32 dt projection.
// ---------------------------------------------------------------------------
template <int WM>
__global__ __launch_bounds__(256) void gemm_small_nt(
    const unsigned short* __restrict__ A, const unsigned short* __restrict__ B,
    float* __restrict__ C, int M, int N, int K, int lda, int ldb, int ldc) {
  const int w = threadIdx.x >> 6;
  const int lane = threadIdx.x & 63;
  const int lm = lane & 15;
  const int ko = (lane >> 4) << 3;
  const int bn0 = blockIdx.x << 6;
  const int m_base = blockIdx.y * (WM * 64) + w * (WM * 16);

  const unsigned short* arow[WM];
#pragma unroll
  for (int i = 0; i < WM; ++i) arow[i] = A + (long long)(m_base + i * 16 + lm) * lda + ko;
  int nv = (N - bn0) >> 4;
  nv = nv > 4 ? 4 : nv;
  const unsigned short* brow[4];
#pragma unroll
  for (int j = 0; j < 4; ++j) {
    int nr = bn0 + j * 16 + lm;
    brow[j] = B + (long long)(j < nv ? nr : 0) * ldb + ko;
  }
  floatx4 acc[WM][4];
#pragma unroll
  for (int i = 0; i < WM; ++i)
#pragma unroll
    for (int j = 0; j < 4; ++j) acc[i][j] = (floatx4){0.f, 0.f, 0.f, 0.f};
  for (int k0 = 0; k0 < K; k0 += 32) {
    bf16x8 a[WM];
#pragma unroll
    for (int i = 0; i < WM; ++i) a[i] = *(const bf16x8*)(arow[i] + k0);
#pragma unroll
    for (int j = 0; j < 4; ++j) {
      if (j < nv) {
        bf16x8 b = *(const bf16x8*)(brow[j] + k0);
#pragma unroll
        for (int i = 0; i < WM; ++i)
          acc[i][j] = __builtin_amdgcn_mfma_f32_16x16x32_bf16(a[i], b, acc[i][j], 0, 0, 0);
      }
    }
  }
  const int r0 = (lane >> 4) << 2;
#pragma unroll
  for (int i = 0; i < WM; ++i)
#pragma unroll
    for (int j = 0; j < 4; ++j)
      if (j < nv) {
        int col = bn0 + j * 16 + lm;
        long long base = (long long)(m_base + i * 16 + r0) * ldc + col;
#pragma unroll
        for (int r = 0; r < 4; ++r) C[base + (long long)r * ldc] = acc[i][j][r];
      }
}

// ---------------------------------------------------------------------------
__global__ __launch_bounds__(256) void f32_to_bf16_k(const float* __restrict__ src,
                                                     unsigned short* __restrict__ dst,
                                                     long long n4) {
  long long i = (long long)blockIdx.x * 256 + threadIdx.x;
  if (i < n4) {
    float4 v = ((const float4*)src)[i];
    ushort4v o = {f32_bf16(v.x), f32_bf16(v.y), f32_bf16(v.z), f32_bf16(v.w)};
    ((ushort4v*)dst)[i] = o;
  }
}

__global__ __launch_bounds__(256) void zero_out_k(float* __restrict__ o, long long n) {
  long long i = (long long)blockIdx.x * 256 + threadIdx.x;
  if (i < n) o[i] = 0.f;
}

// ---------------------------------------------------------------------------
__global__ __launch_bounds__(256) void rmsnorm1024_bf16_k(const float* __restrict__ x,
                                                          const float* __restrict__ w,
                                                          unsigned short* __restrict__ out,
                                                          float eps) {
  long long row = blockIdx.x;
  int t = threadIdx.x;
  float4 v = ((const float4*)(x + row * 1024))[t];
  float ss = v.x * v.x + v.y * v.y + v.z * v.z + v.w * v.w;
  __shared__ float red[4];
#pragma unroll
  for (int o = 32; o > 0; o >>= 1) ss += __shfl_down(ss, o, 64);
  if ((t & 63) == 0) red[t >> 6] = ss;
  __syncthreads();
  float tot = red[0] + red[1] + red[2] + red[3];
  float sc = rsqrtf(tot * (1.0f / 1024.0f) + eps);
  float4 wv = ((const float4*)w)[t];
  ushort4v o = {f32_bf16(v.x * sc * wv.x), f32_bf16(v.y * sc * wv.y),
                f32_bf16(v.z * sc * wv.z), f32_bf16(v.w * sc * wv.w)};
  ((ushort4v*)(out + row * 1024))[t] = o;
}

// ---------------------------------------------------------------------------
// Gated RMSNorm, 2048 cols: g = y(bf16) * silu(z bf16); out bf16
// ---------------------------------------------------------------------------
__global__ __launch_bounds__(256) void gated_rmsnorm2048_k(const unsigned short* __restrict__ y,
                                                           const unsigned short* __restrict__ z,
                                                           const float* __restrict__ w,
                                                           unsigned short* __restrict__ out,
                                                           float eps) {
  long long row = blockIdx.x;
  int t = threadIdx.x;
  ushort8v yv = ((const ushort8v*)(y + row * 2048))[t];
  ushort8v zv = ((const ushort8v*)(z + row * 2048))[t];
  float g[8];
  float ss = 0.f;
#pragma unroll
  for (int j = 0; j < 8; ++j) {
    g[j] = bf2f(yv[j]) * siluf_(bf2f(zv[j]));
    ss += g[j] * g[j];
  }
  __shared__ float red[4];
#pragma unroll
  for (int o = 32; o > 0; o >>= 1) ss += __shfl_down(ss, o, 64);
  if ((t & 63) == 0) red[t >> 6] = ss;
  __syncthreads();
  float tot = red[0] + red[1] + red[2] + red[3];
  float sc = rsqrtf(tot * (1.0f / 2048.0f) + eps);
  float ww[8];
  *(float4*)&ww[0] = ((const float4*)w)[2 * t];
  *(float4*)&ww[4] = ((const float4*)w)[2 * t + 1];
  ushort8v o;
#pragma unroll
  for (int j = 0; j < 8; ++j) o[j] = f32_bf16(g[j] * sc * ww[j]);
  ((ushort8v*)(out + row * 2048))[t] = o;
}

// ---------------------------------------------------------------------------
// Causal depthwise conv (K=4) + bias + silu: xraw bf16 [M,2304] -> xBC bf16
// ---------------------------------------------------------------------------
__global__ __launch_bounds__(256) void conv_silu_k(const unsigned short* __restrict__ xraw,
                                                   const float* __restrict__ wconv,
                                                   const float* __restrict__ bconv,
                                                   unsigned short* __restrict__ xBC) {
  int m = blockIdx.x;
  int l = m & 2047;
  for (int ch = threadIdx.x; ch < 2304; ch += 256) {
    float acc = bconv[ch];
#pragma unroll
    for (int k = 0; k < 4; ++k) {
      int lk = l + k - 3;
      if (lk >= 0) acc += bf2f(xraw[(long long)(m + k - 3) * 2304 + ch]) * wconv[ch * 4 + k];
    }
    xBC[(long long)m * 2304 + ch] = f32_bf16(siluf_(acc));
  }
}

// ---------------------------------------------------------------------------
__global__ __launch_bounds__(256) void dt_softplus_k(const float* __restrict__ dtraw,
                                                     const float* __restrict__ dt_bias,
                                                     float* __restrict__ dt_s) {
  int i = blockIdx.x * 256 + threadIdx.x;
  float xv = dtraw[i] + dt_bias[i & 31];
  dt_s[i] = xv > 20.f ? xv : log1pf(expf(xv));
}

// ---------------------------------------------------------------------------
__global__ __launch_bounds__(128) void dA_cumsum_k(const float* __restrict__ dt_s,
                                                   const float* __restrict__ A_log,
                                                   float* __restrict__ dA_cs) {
  int bi = blockIdx.x;
  int c = bi & 15, h = (bi >> 4) & 31, b = bi >> 9;
  int q = threadIdx.x;
  float A = -expf(A_log[h]);
  float v = dt_s[((long long)(b * 2048 + c * 128 + q)) * 32 + h] * A;
  __shared__ float sbuf[128];
  sbuf[q] = v;
  __syncthreads();
  for (int off = 1; off < 128; off <<= 1) {
    float tv = (q >= off) ? sbuf[q - off] : 0.f;
    __syncthreads();
    sbuf[q] += tv;
    __syncthreads();
  }
  dA_cs[(long long)bi * 128 + q] = sbuf[q];
}

// ---------------------------------------------------------------------------
// S3: Y_diag (-> y bf16) and per-chunk local states (-> states bf16)
// ---------------------------------------------------------------------------
__global__ __launch_bounds__(256) void ssd_diag_states_k(
    const unsigned short* __restrict__ xBC, const float* __restrict__ dt_s,
    const float* __restrict__ dA_cs, const float* __restrict__ G,
    unsigned short* __restrict__ y, unsigned short* __restrict__ states) {
  const int bx = blockIdx.x;
  const int h = bx & 31, c = (bx >> 5) & 15, b = bx >> 9;
  const int t = threadIdx.x;
  __shared__ float xd[128][68];
  __shared__ float Acs[128];
  __shared__ float wdec[128];
  __shared__ float Bst[32][132];
  const long long rowbase = (long long)b * 2048 + c * 128;
  const long long abase = ((long long)((b * 32 + h) * 16 + c)) << 7;
  {
    int s = t >> 1, half = t & 1;
    long long m = rowbase + s;
    float dtv = dt_s[m * 32 + h];
    const ushort8v* xv = (const ushort8v*)(xBC + m * 2304 + h * 64 + half * 32);
    float* dst = &xd[s][half * 32];
#pragma unroll
    for (int i = 0; i < 4; ++i) {
      ushort8v vv = xv[i];
#pragma unroll
      for (int j = 0; j < 8; ++j) dst[i * 8 + j] = bf2f(vv[j]) * dtv;
    }
  }
  if (t < 128) {
    float a = dA_cs[abase + t];
    Acs[t] = a;
    wdec[t] = __expf(dA_cs[abase + 127] - a);
  }
  __syncthreads();
  {
    int q = t >> 1, ph = t & 1;
    float aq = Acs[q];
    const float* Grow = G + (((long long)(b * 16 + c)) * 128 + q) * 128;
    float accd[32];
#pragma unroll
    for (int p = 0; p < 32; ++p) accd[p] = 0.f;
    for (int s = 0; s <= q; ++s) {
      float wgt = Grow[s] * __expf(aq - Acs[s]);
      const float* xr = &xd[s][ph * 32];
#pragma unroll
      for (int p = 0; p < 32; ++p) accd[p] += wgt * xr[p];
    }
    unsigned short* yo = y + (rowbase + q) * 2048 + h * 64 + ph * 32;
#pragma unroll
    for (int i = 0; i < 4; ++i) {
      ushort8v o;
#pragma unroll
      for (int j = 0; j < 8; ++j) o[j] = f32_bf16(accd[i * 8 + j]);
      ((ushort8v*)yo)[i] = o;
    }
  }
  {
    int n = t & 127, phh = t >> 7;
    float accs[32];
#pragma unroll
    for (int p = 0; p < 32; ++p) accs[p] = 0.f;
    for (int sc = 0; sc < 4; ++sc) {
      __syncthreads();
      {
        int sl = t >> 3, vv = t & 7;
        long long m = rowbase + sc * 32 + sl;
        const ushort8v* src = (const ushort8v*)(xBC + m * 2304 + 2048 + vv * 16);
        float* dst = &Bst[sl][vv * 16];
#pragma unroll
        for (int i = 0; i < 2; ++i) {
          ushort8v u = src[i];
#pragma unroll
          for (int j = 0; j < 8; ++j) dst[i * 8 + j] = bf2f(u[j]);
        }
      }
      __syncthreads();
      for (int sl = 0; sl < 32; ++sl) {
        int s = sc * 32 + sl;
        float bv = Bst[sl][n] * wdec[s];
        const float* xr = &xd[s][phh * 32];
#pragma unroll
        for (int p = 0; p < 32; ++p) accs[p] += bv * xr[p];
      }
    }
    unsigned short* st = states + (long long)bx * 8192;
#pragma unroll
    for (int p = 0; p < 32; ++p) st[(long long)(phh * 32 + p) * 128 + n] = f32_bf16(accs[p]);
  }
}

// ---------------------------------------------------------------------------
__global__ __launch_bounds__(256) void ssd_scan_k(const float* __restrict__ dA_cs,
                                                  unsigned short* __restrict__ states) {
  int h = blockIdx.x & 31, b = blockIdx.x >> 5;
  int t = threadIdx.x;
  float carry[32];
#pragma unroll
  for (int i = 0; i < 32; ++i) carry[i] = 0.f;
  for (int c = 0; c < 16; ++c) {
    long long base = ((long long)((b * 16 + c) * 32 + h)) * 8192;
    float dec = __expf(dA_cs[(((long long)((b * 32 + h) * 16 + c)) << 7) + 127]);
#pragma unroll
    for (int i = 0; i < 32; ++i) {
      long long idx = base + t + i * 256;
      float local = bf2f(states[idx]);
      states[idx] = f32_bf16(carry[i]);
      carry[i] = dec * carry[i] + local;
    }
  }
}

// ---------------------------------------------------------------------------
__global__ __launch_bounds__(256) void ssd_off_k(const unsigned short* __restrict__ xBC,
                                                 const float* __restrict__ dA_cs,
                                                 const unsigned short* __restrict__ states,
                                                 const float* __restrict__ Dvec,
                                                 unsigned short* __restrict__ y) {
  const int bx = blockIdx.x;
  const int h = bx & 31, c = (bx >> 5) & 15, b = bx >> 9;
  const int t = threadIdx.x;
  __shared__ float S[128][65];
  __shared__ float eA[128];
  const long long rowbase = (long long)b * 2048 + c * 128;
  const long long abase = ((long long)((b * 32 + h) * 16 + c)) << 7;
  {
    const unsigned short* st = states + (long long)bx * 8192;
    int p = t >> 2, n0 = (t & 3) * 32;
#pragma unroll
    for (int i = 0; i < 32; i += 8) {
      ushort8v v = *(const ushort8v*)(st + (long long)p * 128 + n0 + i);
#pragma unroll
      for (int j = 0; j < 8; ++j) S[n0 + i + j][p] = bf2f(v[j]);
    }
  }
  if (t < 128) eA[t] = __expf(dA_cs[abase + t]);
  __syncthreads();
  int q = t >> 1, ph = t & 1;
  float acc[32];
#pragma unroll
  for (int p = 0; p < 32; ++p) acc[p] = 0.f;
  const unsigned short* Crow = xBC + (rowbase + q) * 2304 + 2176;
  for (int n = 0; n < 128; ++n) {
    float cv = bf2f(Crow[n]);
    const float* sr = &S[n][ph * 32];
#pragma unroll
    for (int p = 0; p < 32; ++p) acc[p] += cv * sr[p];
  }
  float e = eA[q];
  float Dh = Dvec[h];
  const ushort8v* xr = (const ushort8v*)(xBC + (rowbase + q) * 2304 + h * 64 + ph * 32);
  ushort8v* yr = (ushort8v*)(y + (rowbase + q) * 2048 + h * 64 + ph * 32);
#pragma unroll
  for (int i = 0; i < 4; ++i) {
    ushort8v yv = yr[i];
    ushort8v xv = xr[i];
    ushort8v o;
#pragma unroll
    for (int j = 0; j < 8; ++j) {
      float v = bf2f(yv[j]) + e * acc[i * 8 + j] + Dh * bf2f(xv[j]);
      o[j] = f32_bf16(v);
    }
    yr[i] = o;
  }
}

// ---------------------------------------------------------------------------
__global__ __launch_bounds__(256) void add_f32_k(const float* __restrict__ a,
                                                 const float* __restrict__ b,
                                                 float* __restrict__ o, long long n4) {
  long long i = (long long)blockIdx.x * 256 + threadIdx.x;
  if (i < n4) {
    float4 x = ((const float4*)a)[i];
    float4 yv = ((const float4*)b)[i];
    ((float4*)o)[i] = make_float4(x.x + yv.x, x.y + yv.y, x.z + yv.z, x.w + yv.w);
  }
}

// ---------------------------------------------------------------------------
extern "C" void kernel_launch(void* const* d_in, const int* in_sizes, int n_in, void* d_out,
                              int out_size, void* d_ws, size_t ws_size, hipStream_t stream) {
  const float* hs = (const float*)d_in[0];
  const float* w_ln1 = (const float*)d_in[1];
  const float* w_in = (const float*)d_in[2];
  const float* w_conv = (const float*)d_in[3];
  const float* b_conv = (const float*)d_in[4];
  const float* dt_bias = (const float*)d_in[5];
  const float* A_log = (const float*)d_in[6];
  const float* Dvec = (const float*)d_in[7];
  const float* w_mnorm = (const float*)d_in[8];
  const float* w_out = (const float*)d_in[9];
  const float* w_ln2 = (const float*)d_in[10];
  const float* w_gate = (const float*)d_in[11];
  const float* w_up = (const float*)d_in[12];
  const float* w_down = (const float*)d_in[13];
  float* out = (float*)d_out;
  const int M = 4096;

  // arena layout identical to round 1 (all aliased buffers fit their regions)
  char* ws = (char*)d_ws;
  const size_t R0 = 0;               // z bf16 [s3..s11] -> act bf16 [s16..s17]
  const size_t R1 = 33554432;        // xraw bf16 [s3..s4] -> states+y bf16 [s8..s11]
                                     //   -> outtmp fp32 [s12..s13] -> upo bf16 [s15..s16]
                                     //   -> downtmp fp32 [s17..s18]
  const size_t R1b = R1 + 33554432;  // wbf_out [s4b..s12]
  const size_t R2 = 71303168;        // xBC bf16 [s4..s10] -> ygn [s11..s12] -> h2 [s14..s16]
  const size_t R3 = 90177536;        // hnorm+wbf_in [s1..s3] -> dt_s/dA/G [s5..s10] -> mh [s13..s18]
  const size_t R4 = 107544576;       // dtraw fp32 [s3..s5]
  const size_t W0 = 108068864;       // wbf_gate | wbf_up | wbf_down
  const size_t NEED = 133234688;

  if (ws_size < NEED) {
    hipLaunchKernelGGL(zero_out_k, dim3((out_size + 255) / 256), dim3(256), 0, stream, out,
                       (long long)out_size);
    return;
  }

  unsigned short* z = (unsigned short*)(ws + R0);
  unsigned short* act = (unsigned short*)(ws + R0);
  unsigned short* xraw = (unsigned short*)(ws + R1);
  unsigned short* states = (unsigned short*)(ws + R1);
  unsigned short* ybuf = (unsigned short*)(ws + R1 + 16777216);
  float* outtmp = (float*)(ws + R1);
  unsigned short* upo = (unsigned short*)(ws + R1);
  float* downtmp = (float*)(ws + R1);
  unsigned short* wbf_out = (unsigned short*)(ws + R1b);
  unsigned short* xBC = (unsigned short*)(ws + R2);
  unsigned short* ygn = (unsigned short*)(ws + R2);
  unsigned short* h2 = (unsigned short*)(ws + R2);
  unsigned short* hnorm = (unsigned short*)(ws + R3);
  unsigned short* wbf_in = (unsigned short*)(ws + R3 + 8388608);
  float* dt_s = (float*)(ws + R3);
  float* dA_cs = (float*)(ws + R3 + 524288);
  float* Gbuf = (float*)(ws + R3 + 1048576);
  float* mh = (float*)(ws + R3);
  float* dtraw = (float*)(ws + R4);
  unsigned short* wbf_gate = (unsigned short*)(ws + W0);
  unsigned short* wbf_up = (unsigned short*)(ws + W0 + 8388608);
  unsigned short* wbf_down = (unsigned short*)(ws + W0 + 16777216);

  // s1: rmsnorm(ln1) -> hnorm bf16
  hipLaunchKernelGGL(rmsnorm1024_bf16_k, dim3(M), dim3(256), 0, stream, hs, w_ln1, hnorm, 1e-6f);
  // s2: weight conversions
  hipLaunchKernelGGL(f32_to_bf16_k, dim3(4384), dim3(256), 0, stream, w_in, wbf_in, 1122304LL);
  hipLaunchKernelGGL(f32_to_bf16_k, dim3(4096), dim3(256), 0, stream, w_gate, wbf_gate, 1048576LL);
  hipLaunchKernelGGL(f32_to_bf16_k, dim3(4096), dim3(256), 0, stream, w_up, wbf_up, 1048576LL);
  hipLaunchKernelGGL(f32_to_bf16_k, dim3(4096), dim3(256), 0, stream, w_down, wbf_down, 1048576LL);
  // s3: in_proj -> z bf16 / xraw bf16 / dtraw fp32
  hipLaunchKernelGGL((gemm128<1>), dim3(16, 32, 1), dim3(256), 0, stream, hnorm, wbf_in, (void*)z,
                     (const unsigned short*)nullptr, 1024, 1024, 1024, 2048, 0LL, 0LL, 0LL);
  hipLaunchKernelGGL((gemm128<1>), dim3(18, 32, 1), dim3(256), 0, stream, hnorm,
                     wbf_in + 2048 * 1024, (void*)xraw, (const unsigned short*)nullptr, 1024, 1024,
                     1024, 2304, 0LL, 0LL, 0LL);
  hipLaunchKernelGGL((gemm_small_nt<4>), dim3(1, 16, 1), dim3(256), 0, stream, hnorm,
                     wbf_in + 4352 * 1024, dtraw, M, 32, 1024, 1024, 1024, 32);
  // s4: conv + silu -> xBC bf16
  hipLaunchKernelGGL(conv_silu_k, dim3(M), dim3(256), 0, stream, xraw, w_conv, b_conv, xBC);
  // s4b: w_out conversion
  hipLaunchKernelGGL(f32_to_bf16_k, dim3(2048), dim3(256), 0, stream, w_out, wbf_out, 524288LL);
  // s5: dt softplus
  hipLaunchKernelGGL(dt_softplus_k, dim3(512), dim3(256), 0, stream, dtraw, dt_bias, dt_s);
  // s6: dA cumsum
  hipLaunchKernelGGL(dA_cumsum_k, dim3(1024), dim3(128), 0, stream, dt_s, A_log, dA_cs);
  // s7: G = C @ B^T per chunk (batched over 32 chunks)
  hipLaunchKernelGGL((gemm128<0>), dim3(1, 1, 32), dim3(256), 0, stream, xBC + 2176, xBC + 2048,
                     (void*)Gbuf, (const unsigned short*)nullptr, 128, 2304, 2304, 128, 294912LL,
                     294912LL, 16384LL);
  // s8: Y_diag + local states
  hipLaunchKernelGGL(ssd_diag_states_k, dim3(1024), dim3(256), 0, stream, xBC, dt_s, dA_cs, Gbuf,
                     ybuf, states);
  // s9: inter-chunk scan
  hipLaunchKernelGGL(ssd_scan_k, dim3(64), dim3(256), 0, stream, dA_cs, states);
  // s10: Y_off + D-skip
  hipLaunchKernelGGL(ssd_off_k, dim3(1024), dim3(256), 0, stream, xBC, dA_cs, states, Dvec, ybuf);
  // s11: gated rmsnorm -> ygn bf16
  hipLaunchKernelGGL(gated_rmsnorm2048_k, dim3(M), dim3(256), 0, stream, ybuf, z, w_mnorm, ygn,
                     1e-5f);
  // s12: out_proj -> outtmp fp32
  hipLaunchKernelGGL((gemm128<0>), dim3(8, 32, 1), dim3(256), 0, stream, ygn, wbf_out,
                     (void*)outtmp, (const unsigned short*)nullptr, 2048, 2048, 2048, 1024, 0LL,
                     0LL, 0LL);
  // s13: residual add -> mh
  hipLaunchKernelGGL(add_f32_k, dim3(4096), dim3(256), 0, stream, hs, outtmp, mh, 1048576LL);
  // s14: rmsnorm(ln2) -> h2 bf16
  hipLaunchKernelGGL(rmsnorm1024_bf16_k, dim3(M), dim3(256), 0, stream, mh, w_ln2, h2, 1e-6f);
  // s15: up -> upo bf16
  hipLaunchKernelGGL((gemm128<1>), dim3(32, 32, 1), dim3(256), 0, stream, h2, wbf_up, (void*)upo,
                     (const unsigned short*)nullptr, 1024, 1024, 1024, 4096, 0LL, 0LL, 0LL);
  // s16: gate with fused swiglu -> act bf16
  hipLaunchKernelGGL((gemm128<2>), dim3(32, 32, 1), dim3(256), 0, stream, h2, wbf_gate, (void*)act,
                     upo, 1024, 1024, 1024, 4096, 0LL, 0LL, 0LL);
  // s17: down -> downtmp fp32
  hipLaunchKernelGGL((gemm128<0>), dim3(8, 32, 1), dim3(256), 0, stream, act, wbf_down,
                     (void*)downtmp, (const unsigned short*)nullptr, 4096, 4096, 4096, 1024, 0LL,
                     0LL, 0LL);
  // s18: final residual add -> out
  hipLaunchKernelGGL(add_f32_k, dim3(4096), dim3(256), 0, stream, mh, downtmp, out, 1048576LL);
}

// Round 4
// 673.822 us; speedup vs baseline: 1.6473x; 1.2110x over previous
//
#include <hip/hip_runtime.h>

#define DEV static __device__ __forceinline__

typedef short bf16x8 __attribute__((ext_vector_type(8)));
typedef float floatx4 __attribute__((ext_vector_type(4)));
typedef unsigned short ushort4v __attribute__((ext_vector_type(4)));
typedef unsigned short ushort8v __attribute__((ext_vector_type(8)));

DEV unsigned short f32_bf16(float f) {
  unsigned int u = __builtin_bit_cast(unsigned int, f);
  u = u + 0x7fffu + ((u >> 16) & 1u);
  return (unsigned short)(u >> 16);
}
DEV float bf2f(unsigned short u) {
  unsigned int v = ((unsigned int)u) << 16;
  return __builtin_bit_cast(float, v);
}
DEV float sigmoidf_(float x) { return 1.0f / (1.0f + __expf(-x)); }
DEV float siluf_(float x) { return x * sigmoidf_(x); }

#define GLD_LDS16(g, l)                                                              \
  __builtin_amdgcn_global_load_lds((const __attribute__((address_space(1))) void*)(g), \
                                   (__attribute__((address_space(3))) void*)(l), 16, 0, 0)

// ---------------------------------------------------------------------------
// m97-style MFMA GEMM: C[M,N] = A[M,K] @ B[N,K]^T, bf16 in, 128x128 block tile,
// BK=32, LDS staging via global_load_lds(16B), XOR-swizzled k-chunks.
// MODE 0: fp32 store. 1: bf16. 2: bf16(silu(acc)*other).
// ---------------------------------------------------------------------------
template <int MODE>
__global__ __launch_bounds__(256) void gemm128(
    const unsigned short* __restrict__ A, const unsigned short* __restrict__ B,
    void* __restrict__ Cv, const unsigned short* __restrict__ other,
    int K, int lda, int ldb, int ldc, long long bsA, long long bsB, long long bsC) {
  __shared__ unsigned short As[128 * 32];
  __shared__ unsigned short Bs[128 * 32];
  A += (long long)blockIdx.z * bsA;
  B += (long long)blockIdx.z * bsB;
  const long long coff = (long long)blockIdx.z * bsC;
  const int tid = threadIdx.x;
  const int w = tid >> 6, lane = tid & 63;
  const int m0 = blockIdx.y << 7, n0 = blockIdx.x << 7;

  const int srow = lane >> 2;
  const int schunk = ((lane & 3) ^ (srow & 3)) * 8;
  const unsigned short* ag0 = A + (long long)(m0 + w * 32 + srow) * lda + schunk;
  const unsigned short* ag1 = ag0 + (long long)16 * lda;
  const unsigned short* bg0 = B + (long long)(n0 + w * 32 + srow) * ldb + schunk;
  const unsigned short* bg1 = bg0 + (long long)16 * ldb;
  unsigned short* al0 = As + (w * 32) * 32 + lane * 8;
  unsigned short* al1 = As + (w * 32 + 16) * 32 + lane * 8;
  unsigned short* bl0 = Bs + (w * 32) * 32 + lane * 8;
  unsigned short* bl1 = Bs + (w * 32 + 16) * 32 + lane * 8;

  const int wr = (w >> 1) << 6, wc = (w & 1) << 6;
  const int fr = lane & 15;
  const int slot = (((lane >> 4) ^ (fr & 3))) << 3;

  floatx4 acc[4][4];
#pragma unroll
  for (int i = 0; i < 4; ++i)
#pragma unroll
    for (int j = 0; j < 4; ++j) acc[i][j] = (floatx4){0.f, 0.f, 0.f, 0.f};

  for (int k0 = 0; k0 < K; k0 += 32) {
    __syncthreads();
    GLD_LDS16(ag0 + k0, al0);
    GLD_LDS16(ag1 + k0, al1);
    GLD_LDS16(bg0 + k0, bl0);
    GLD_LDS16(bg1 + k0, bl1);
    __syncthreads();
    bf16x8 af[4], bf_[4];
#pragma unroll
    for (int i = 0; i < 4; ++i)
      af[i] = *(const bf16x8*)(As + (wr + i * 16 + fr) * 32 + slot);
#pragma unroll
    for (int j = 0; j < 4; ++j)
      bf_[j] = *(const bf16x8*)(Bs + (wc + j * 16 + fr) * 32 + slot);
#pragma unroll
    for (int i = 0; i < 4; ++i)
#pragma unroll
      for (int j = 0; j < 4; ++j)
        acc[i][j] = __builtin_amdgcn_mfma_f32_16x16x32_bf16(af[i], bf_[j], acc[i][j], 0, 0, 0);
  }

  const int r0 = (lane >> 4) << 2;
#pragma unroll
  for (int i = 0; i < 4; ++i) {
#pragma unroll
    for (int j = 0; j < 4; ++j) {
      long long base = (long long)(m0 + wr + i * 16 + r0) * ldc + (n0 + wc + j * 16 + fr);
#pragma unroll
      for (int r = 0; r < 4; ++r) {
        long long idx = coff + base + (long long)r * ldc;
        float v = acc[i][j][r];
        if constexpr (MODE == 0) {
          ((float*)Cv)[idx] = v;
        } else if constexpr (MODE == 1) {
          ((unsigned short*)Cv)[idx] = f32_bf16(v);
        } else {
          ((unsigned short*)Cv)[idx] = f32_bf16(siluf_(v) * bf2f(other[idx]));
        }
      }
    }
  }
}

// ---------------------------------------------------------------------------
// small GEMM (direct-from-global), used only for the N=32 dt projection.
// ---------------------------------------------------------------------------
template <int WM>
__global__ __launch_bounds__(256) void gemm_small_nt(
    const unsigned short* __restrict__ A, const unsigned short* __restrict__ B,
    float* __restrict__ C, int M, int N, int K, int lda, int ldb, int ldc) {
  const int w = threadIdx.x >> 6;
  const int lane = threadIdx.x & 63;
  const int lm = lane & 15;
  const int ko = (lane >> 4) << 3;
  const int bn0 = blockIdx.x << 6;
  const int m_base = blockIdx.y * (WM * 64) + w * (WM * 16);

  const unsigned short* arow[WM];
#pragma unroll
  for (int i = 0; i < WM; ++i) arow[i] = A + (long long)(m_base + i * 16 + lm) * lda + ko;
  int nv = (N - bn0) >> 4;
  nv = nv > 4 ? 4 : nv;
  const unsigned short* brow[4];
#pragma unroll
  for (int j = 0; j < 4; ++j) {
    int nr = bn0 + j * 16 + lm;
    brow[j] = B + (long long)(j < nv ? nr : 0) * ldb + ko;
  }
  floatx4 acc[WM][4];
#pragma unroll
  for (int i = 0; i < WM; ++i)
#pragma unroll
    for (int j = 0; j < 4; ++j) acc[i][j] = (floatx4){0.f, 0.f, 0.f, 0.f};
  for (int k0 = 0; k0 < K; k0 += 32) {
    bf16x8 a[WM];
#pragma unroll
    for (int i = 0; i < WM; ++i) a[i] = *(const bf16x8*)(arow[i] + k0);
#pragma unroll
    for (int j = 0; j < 4; ++j) {
      if (j < nv) {
        bf16x8 b = *(const bf16x8*)(brow[j] + k0);
#pragma unroll
        for (int i = 0; i < WM; ++i)
          acc[i][j] = __builtin_amdgcn_mfma_f32_16x16x32_bf16(a[i], b, acc[i][j], 0, 0, 0);
      }
    }
  }
  const int r0 = (lane >> 4) << 2;
#pragma unroll
  for (int i = 0; i < WM; ++i)
#pragma unroll
    for (int j = 0; j < 4; ++j)
      if (j < nv) {
        int col = bn0 + j * 16 + lm;
        long long base = (long long)(m_base + i * 16 + r0) * ldc + col;
#pragma unroll
        for (int r = 0; r < 4; ++r) C[base + (long long)r * ldc] = acc[i][j][r];
      }
}

// ---------------------------------------------------------------------------
__global__ __launch_bounds__(256) void f32_to_bf16_k(const float* __restrict__ src,
                                                     unsigned short* __restrict__ dst,
                                                     long long n4) {
  long long i = (long long)blockIdx.x * 256 + threadIdx.x;
  if (i < n4) {
    float4 v = ((const float4*)src)[i];
    ushort4v o = {f32_bf16(v.x), f32_bf16(v.y), f32_bf16(v.z), f32_bf16(v.w)};
    ((ushort4v*)dst)[i] = o;
  }
}

__global__ __launch_bounds__(256) void zero_out_k(float* __restrict__ o, long long n) {
  long long i = (long long)blockIdx.x * 256 + threadIdx.x;
  if (i < n) o[i] = 0.f;
}

// ---------------------------------------------------------------------------
__global__ __launch_bounds__(256) void rmsnorm1024_bf16_k(const float* __restrict__ x,
                                                          const float* __restrict__ w,
                                                          unsigned short* __restrict__ out,
                                                          float eps) {
  long long row = blockIdx.x;
  int t = threadIdx.x;
  float4 v = ((const float4*)(x + row * 1024))[t];
  float ss = v.x * v.x + v.y * v.y + v.z * v.z + v.w * v.w;
  __shared__ float red[4];
#pragma unroll
  for (int o = 32; o > 0; o >>= 1) ss += __shfl_down(ss, o, 64);
  if ((t & 63) == 0) red[t >> 6] = ss;
  __syncthreads();
  float tot = red[0] + red[1] + red[2] + red[3];
  float sc = rsqrtf(tot * (1.0f / 1024.0f) + eps);
  float4 wv = ((const float4*)w)[t];
  ushort4v o = {f32_bf16(v.x * sc * wv.x), f32_bf16(v.y * sc * wv.y),
                f32_bf16(v.z * sc * wv.z), f32_bf16(v.w * sc * wv.w)};
  ((ushort4v*)(out + row * 1024))[t] = o;
}

// ---------------------------------------------------------------------------
__global__ __launch_bounds__(256) void gated_rmsnorm2048_k(const unsigned short* __restrict__ y,
                                                           const unsigned short* __restrict__ z,
                                                           const float* __restrict__ w,
                                                           unsigned short* __restrict__ out,
                                                           float eps) {
  long long row = blockIdx.x;
  int t = threadIdx.x;
  ushort8v yv = ((const ushort8v*)(y + row * 2048))[t];
  ushort8v zv = ((const ushort8v*)(z + row * 2048))[t];
  float g[8];
  float ss = 0.f;
#pragma unroll
  for (int j = 0; j < 8; ++j) {
    g[j] = bf2f(yv[j]) * siluf_(bf2f(zv[j]));
    ss += g[j] * g[j];
  }
  __shared__ float red[4];
#pragma unroll
  for (int o = 32; o > 0; o >>= 1) ss += __shfl_down(ss, o, 64);
  if ((t & 63) == 0) red[t >> 6] = ss;
  __syncthreads();
  float tot = red[0] + red[1] + red[2] + red[3];
  float sc = rsqrtf(tot * (1.0f / 2048.0f) + eps);
  float ww[8];
  *(float4*)&ww[0] = ((const float4*)w)[2 * t];
  *(float4*)&ww[4] = ((const float4*)w)[2 * t + 1];
  ushort8v o;
#pragma unroll
  for (int j = 0; j < 8; ++j) o[j] = f32_bf16(g[j] * sc * ww[j]);
  ((ushort8v*)(out + row * 2048))[t] = o;
}

// ---------------------------------------------------------------------------
__global__ __launch_bounds__(256) void conv_silu_k(const unsigned short* __restrict__ xraw,
                                                   const float* __restrict__ wconv,
                                                   const float* __restrict__ bconv,
                                                   unsigned short* __restrict__ xBC) {
  int m = blockIdx.x;
  int l = m & 2047;
  for (int ch = threadIdx.x; ch < 2304; ch += 256) {
    float acc = bconv[ch];
#pragma unroll
    for (int k = 0; k < 4; ++k) {
      int lk = l + k - 3;
      if (lk >= 0) acc += bf2f(xraw[(long long)(m + k - 3) * 2304 + ch]) * wconv[ch * 4 + k];
    }
    xBC[(long long)m * 2304 + ch] = f32_bf16(siluf_(acc));
  }
}

// ---------------------------------------------------------------------------
__global__ __launch_bounds__(256) void dt_softplus_k(const float* __restrict__ dtraw,
                                                     const float* __restrict__ dt_bias,
                                                     float* __restrict__ dt_s) {
  int i = blockIdx.x * 256 + threadIdx.x;
  float xv = dtraw[i] + dt_bias[i & 31];
  dt_s[i] = xv > 20.f ? xv : log1pf(expf(xv));
}

// ---------------------------------------------------------------------------
__global__ __launch_bounds__(128) void dA_cumsum_k(const float* __restrict__ dt_s,
                                                   const float* __restrict__ A_log,
                                                   float* __restrict__ dA_cs) {
  int bi = blockIdx.x;
  int c = bi & 15, h = (bi >> 4) & 31, b = bi >> 9;
  int q = threadIdx.x;
  float A = -expf(A_log[h]);
  float v = dt_s[((long long)(b * 2048 + c * 128 + q)) * 32 + h] * A;
  __shared__ float sbuf[128];
  sbuf[q] = v;
  __syncthreads();
  for (int off = 1; off < 128; off <<= 1) {
    float tv = (q >= off) ? sbuf[q - off] : 0.f;
    __syncthreads();
    sbuf[q] += tv;
    __syncthreads();
  }
  dA_cs[(long long)bi * 128 + q] = sbuf[q];
}

// ---------------------------------------------------------------------------
// S3 (MFMA): Y_diag -> y bf16, local states -> states bf16.
// M[q][s] = G[q,s]*exp(Acs[q]-Acs[s]) (causal) in LDS bf16, xdT[p][s] in LDS.
// Then B~[n][s] = B[s,n]*wdec[s] reuses M's buffer. blockIdx = b*512+c*32+h.
// ---------------------------------------------------------------------------
__global__ __launch_bounds__(256) void ssd_diag_states_k(
    const unsigned short* __restrict__ xBC, const float* __restrict__ dt_s,
    const float* __restrict__ dA_cs, const unsigned short* __restrict__ G,
    unsigned short* __restrict__ y, unsigned short* __restrict__ states) {
  __shared__ unsigned short Mz[128 * 136];   // stride 136 ushorts = 272 B (16B-aligned)
  __shared__ unsigned short xdT[64 * 136];
  __shared__ float Acs[128];
  __shared__ float wdec[128];
  const int bx = blockIdx.x;
  const int h = bx & 31, c = (bx >> 5) & 15, b = bx >> 9;
  const int t = threadIdx.x;
  const int w = t >> 6, lane = t & 63, fr = lane & 15, hi = lane >> 4;
  const long long rowbase = (long long)b * 2048 + c * 128;
  const long long abase = ((long long)((b * 32 + h) * 16 + c)) << 7;

  if (t < 128) {
    float a = dA_cs[abase + t];
    Acs[t] = a;
    wdec[t] = __expf(dA_cs[abase + 127] - a);
  }
  // xdT[p][s] = x[s][p] * dt[s]
  {
    int s = t >> 1, p0 = (t & 1) * 32;
    float dtv = dt_s[(rowbase + s) * 32 + h];
    const ushort8v* xv = (const ushort8v*)(xBC + (rowbase + s) * 2304 + h * 64 + p0);
#pragma unroll
    for (int i = 0; i < 4; ++i) {
      ushort8v vv = xv[i];
#pragma unroll
      for (int j = 0; j < 8; ++j) xdT[(p0 + i * 8 + j) * 136 + s] = f32_bf16(bf2f(vv[j]) * dtv);
    }
  }
  __syncthreads();
  // M[q][s]
  {
    int q = t >> 1, s0 = (t & 1) * 64;
    float aq = Acs[q];
    const ushort8v* gv =
        (const ushort8v*)(G + (((long long)(b * 16 + c)) * 128 + q) * 128 + s0);
#pragma unroll
    for (int i = 0; i < 8; ++i) {
      ushort8v gg = gv[i];
#pragma unroll
      for (int j = 0; j < 8; ++j) {
        int s = s0 + i * 8 + j;
        float m = (s <= q) ? bf2f(gg[j]) * __expf(aq - Acs[s]) : 0.f;
        Mz[q * 136 + s] = f32_bf16(m);
      }
    }
  }
  __syncthreads();
  // Y = M @ xdT^T   (wave w: q in [w*32, w*32+32))
  const int q0 = w << 5;
  {
    floatx4 acc[2][4];
#pragma unroll
    for (int i = 0; i < 2; ++i)
#pragma unroll
      for (int j = 0; j < 4; ++j) acc[i][j] = (floatx4){0.f, 0.f, 0.f, 0.f};
#pragma unroll
    for (int k0 = 0; k0 < 128; k0 += 32) {
      int kk = k0 + hi * 8;
      bf16x8 a0 = *(const bf16x8*)(Mz + (q0 + fr) * 136 + kk);
      bf16x8 a1 = *(const bf16x8*)(Mz + (q0 + 16 + fr) * 136 + kk);
      bf16x8 bf_[4];
#pragma unroll
      for (int j = 0; j < 4; ++j) bf_[j] = *(const bf16x8*)(xdT + (j * 16 + fr) * 136 + kk);
#pragma unroll
      for (int j = 0; j < 4; ++j) {
        acc[0][j] = __builtin_amdgcn_mfma_f32_16x16x32_bf16(a0, bf_[j], acc[0][j], 0, 0, 0);
        acc[1][j] = __builtin_amdgcn_mfma_f32_16x16x32_bf16(a1, bf_[j], acc[1][j], 0, 0, 0);
      }
    }
#pragma unroll
    for (int i = 0; i < 2; ++i)
#pragma unroll
      for (int r = 0; r < 4; ++r) {
        int q = q0 + i * 16 + hi * 4 + r;
        unsigned short* yrow = y + (rowbase + q) * 2048 + h * 64;
#pragma unroll
        for (int j = 0; j < 4; ++j) yrow[j * 16 + fr] = f32_bf16(acc[i][j][r]);
      }
  }
  __syncthreads();
  // B~[n][s] = B[s][n] * wdec[s]  (reuse Mz)
  {
    int s = t >> 1, n0 = (t & 1) * 64;
    float wd = wdec[s];
    const ushort8v* bv = (const ushort8v*)(xBC + (rowbase + s) * 2304 + 2048 + n0);
#pragma unroll
    for (int i = 0; i < 8; ++i) {
      ushort8v bb = bv[i];
#pragma unroll
      for (int j = 0; j < 8; ++j) Mz[(n0 + i * 8 + j) * 136 + s] = f32_bf16(bf2f(bb[j]) * wd);
    }
  }
  __syncthreads();
  // states[n][p] = B~ @ xdT^T  -> store st[p*128+n]  (wave w: n in [w*32, ..))
  {
    floatx4 acc[2][4];
#pragma unroll
    for (int i = 0; i < 2; ++i)
#pragma unroll
      for (int j = 0; j < 4; ++j) acc[i][j] = (floatx4){0.f, 0.f, 0.f, 0.f};
#pragma unroll
    for (int k0 = 0; k0 < 128; k0 += 32) {
      int kk = k0 + hi * 8;
      bf16x8 a0 = *(const bf16x8*)(Mz + (q0 + fr) * 136 + kk);
      bf16x8 a1 = *(const bf16x8*)(Mz + (q0 + 16 + fr) * 136 + kk);
      bf16x8 bf_[4];
#pragma unroll
      for (int j = 0; j < 4; ++j) bf_[j] = *(const bf16x8*)(xdT + (j * 16 + fr) * 136 + kk);
#pragma unroll
      for (int j = 0; j < 4; ++j) {
        acc[0][j] = __builtin_amdgcn_mfma_f32_16x16x32_bf16(a0, bf_[j], acc[0][j], 0, 0, 0);
        acc[1][j] = __builtin_amdgcn_mfma_f32_16x16x32_bf16(a1, bf_[j], acc[1][j], 0, 0, 0);
      }
    }
    unsigned short* st = states + (long long)bx * 8192;
#pragma unroll
    for (int i = 0; i < 2; ++i)
#pragma unroll
      for (int j = 0; j < 4; ++j) {
        int p = j * 16 + fr;
        int n = q0 + i * 16 + hi * 4;
        ushort4v o;
#pragma unroll
        for (int r = 0; r < 4; ++r) o[r] = f32_bf16(acc[i][j][r]);
        *(ushort4v*)(st + p * 128 + n) = o;
      }
  }
}

// ---------------------------------------------------------------------------
__global__ __launch_bounds__(256) void ssd_scan_k(const float* __restrict__ dA_cs,
                                                  unsigned short* __restrict__ states) {
  int h = blockIdx.x & 31, b = blockIdx.x >> 5;
  int t = threadIdx.x;
  float carry[32];
#pragma unroll
  for (int i = 0; i < 32; ++i) carry[i] = 0.f;
  for (int c = 0; c < 16; ++c) {
    long long base = ((long long)((b * 16 + c) * 32 + h)) * 8192;
    float dec = __expf(dA_cs[(((long long)((b * 32 + h) * 16 + c)) << 7) + 127]);
#pragma unroll
    for (int i = 0; i < 32; ++i) {
      long long idx = base + t + i * 256;
      float local = bf2f(states[idx]);
      states[idx] = f32_bf16(carry[i]);
      carry[i] = dec * carry[i] + local;
    }
  }
}

// ---------------------------------------------------------------------------
// S5 (MFMA, no LDS matmul): y += eA[q] * (C @ st^T) + D[h]*x.  A,B direct global.
// ---------------------------------------------------------------------------
__global__ __launch_bounds__(256) void ssd_off_k(const unsigned short* __restrict__ xBC,
                                                 const float* __restrict__ dA_cs,
                                                 const unsigned short* __restrict__ states,
                                                 const float* __restrict__ Dvec,
                                                 unsigned short* __restrict__ y) {
  __shared__ float eA[128];
  const int bx = blockIdx.x;
  const int h = bx & 31, c = (bx >> 5) & 15, b = bx >> 9;
  const int t = threadIdx.x;
  const int w = t >> 6, lane = t & 63, fr = lane & 15, hi = lane >> 4;
  const long long rowbase = (long long)b * 2048 + c * 128;
  const long long abase = ((long long)((b * 32 + h) * 16 + c)) << 7;
  if (t < 128) eA[t] = __expf(dA_cs[abase + t]);
  __syncthreads();

  const unsigned short* st = states + (long long)bx * 8192;
  const int q0 = w << 5;
  floatx4 acc[2][4];
#pragma unroll
  for (int i = 0; i < 2; ++i)
#pragma unroll
    for (int j = 0; j < 4; ++j) acc[i][j] = (floatx4){0.f, 0.f, 0.f, 0.f};

#pragma unroll
  for (int k0 = 0; k0 < 128; k0 += 32) {
    int kk = k0 + hi * 8;
    bf16x8 a0 = *(const bf16x8*)(xBC + (rowbase + q0 + fr) * 2304 + 2176 + kk);
    bf16x8 a1 = *(const bf16x8*)(xBC + (rowbase + q0 + 16 + fr) * 2304 + 2176 + kk);
    bf16x8 bf_[4];
#pragma unroll
    for (int j = 0; j < 4; ++j) bf_[j] = *(const bf16x8*)(st + (j * 16 + fr) * 128 + kk);
#pragma unroll
    for (int j = 0; j < 4; ++j) {
      acc[0][j] = __builtin_amdgcn_mfma_f32_16x16x32_bf16(a0, bf_[j], acc[0][j], 0, 0, 0);
      acc[1][j] = __builtin_amdgcn_mfma_f32_16x16x32_bf16(a1, bf_[j], acc[1][j], 0, 0, 0);
    }
  }

  float Dh = Dvec[h];
#pragma unroll
  for (int i = 0; i < 2; ++i) {
#pragma unroll
    for (int r = 0; r < 4; ++r) {
      int q = q0 + i * 16 + hi * 4 + r;
      float e = eA[q];
      const unsigned short* xrow = xBC + (rowbase + q) * 2304 + h * 64;
      unsigned short* yrow = y + (rowbase + q) * 2048 + h * 64;
#pragma unroll
      for (int j = 0; j < 4; ++j) {
        int p = j * 16 + fr;
        float v = bf2f(yrow[p]) + e * acc[i][j][r] + Dh * bf2f(xrow[p]);
        yrow[p] = f32_bf16(v);
      }
    }
  }
}

// ---------------------------------------------------------------------------
__global__ __launch_bounds__(256) void add_f32_k(const float* __restrict__ a,
                                                 const float* __restrict__ b,
                                                 float* __restrict__ o, long long n4) {
  long long i = (long long)blockIdx.x * 256 + threadIdx.x;
  if (i < n4) {
    float4 x = ((const float4*)a)[i];
    float4 yv = ((const float4*)b)[i];
    ((float4*)o)[i] = make_float4(x.x + yv.x, x.y + yv.y, x.z + yv.z, x.w + yv.w);
  }
}

// ---------------------------------------------------------------------------
extern "C" void kernel_launch(void* const* d_in, const int* in_sizes, int n_in, void* d_out,
                              int out_size, void* d_ws, size_t ws_size, hipStream_t stream) {
  const float* hs = (const float*)d_in[0];
  const float* w_ln1 = (const float*)d_in[1];
  const float* w_in = (const float*)d_in[2];
  const float* w_conv = (const float*)d_in[3];
  const float* b_conv = (const float*)d_in[4];
  const float* dt_bias = (const float*)d_in[5];
  const float* A_log = (const float*)d_in[6];
  const float* Dvec = (const float*)d_in[7];
  const float* w_mnorm = (const float*)d_in[8];
  const float* w_out = (const float*)d_in[9];
  const float* w_ln2 = (const float*)d_in[10];
  const float* w_gate = (const float*)d_in[11];
  const float* w_up = (const float*)d_in[12];
  const float* w_down = (const float*)d_in[13];
  float* out = (float*)d_out;
  const int M = 4096;

  char* ws = (char*)d_ws;
  const size_t R0 = 0;               // z bf16 -> act bf16
  const size_t R1 = 33554432;        // xraw bf16 -> states+y bf16 -> outtmp fp32 -> upo -> downtmp
  const size_t R1b = R1 + 33554432;  // wbf_out
  const size_t R2 = 71303168;        // xBC bf16 -> ygn -> h2
  const size_t R3 = 90177536;        // hnorm+wbf_in -> dt_s/dA/G -> mh
  const size_t R4 = 107544576;       // dtraw fp32
  const size_t W0 = 108068864;       // wbf_gate | wbf_up | wbf_down
  const size_t NEED = 133234688;

  if (ws_size < NEED) {
    hipLaunchKernelGGL(zero_out_k, dim3((out_size + 255) / 256), dim3(256), 0, stream, out,
                       (long long)out_size);
    return;
  }

  unsigned short* z = (unsigned short*)(ws + R0);
  unsigned short* act = (unsigned short*)(ws + R0);
  unsigned short* xraw = (unsigned short*)(ws + R1);
  unsigned short* states = (unsigned short*)(ws + R1);
  unsigned short* ybuf = (unsigned short*)(ws + R1 + 16777216);
  float* outtmp = (float*)(ws + R1);
  unsigned short* upo = (unsigned short*)(ws + R1);
  float* downtmp = (float*)(ws + R1);
  unsigned short* wbf_out = (unsigned short*)(ws + R1b);
  unsigned short* xBC = (unsigned short*)(ws + R2);
  unsigned short* ygn = (unsigned short*)(ws + R2);
  unsigned short* h2 = (unsigned short*)(ws + R2);
  unsigned short* hnorm = (unsigned short*)(ws + R3);
  unsigned short* wbf_in = (unsigned short*)(ws + R3 + 8388608);
  float* dt_s = (float*)(ws + R3);
  float* dA_cs = (float*)(ws + R3 + 524288);
  unsigned short* Gbuf = (unsigned short*)(ws + R3 + 1048576);
  float* mh = (float*)(ws + R3);
  float* dtraw = (float*)(ws + R4);
  unsigned short* wbf_gate = (unsigned short*)(ws + W0);
  unsigned short* wbf_up = (unsigned short*)(ws + W0 + 8388608);
  unsigned short* wbf_down = (unsigned short*)(ws + W0 + 16777216);

  // s1: rmsnorm(ln1) -> hnorm bf16
  hipLaunchKernelGGL(rmsnorm1024_bf16_k, dim3(M), dim3(256), 0, stream, hs, w_ln1, hnorm, 1e-6f);
  // s2: weight conversions
  hipLaunchKernelGGL(f32_to_bf16_k, dim3(4384), dim3(256), 0, stream, w_in, wbf_in, 1122304LL);
  hipLaunchKernelGGL(f32_to_bf16_k, dim3(4096), dim3(256), 0, stream, w_gate, wbf_gate, 1048576LL);
  hipLaunchKernelGGL(f32_to_bf16_k, dim3(4096), dim3(256), 0, stream, w_up, wbf_up, 1048576LL);
  hipLaunchKernelGGL(f32_to_bf16_k, dim3(4096), dim3(256), 0, stream, w_down, wbf_down, 1048576LL);
  // s3: in_proj -> z bf16 / xraw bf16 / dtraw fp32
  hipLaunchKernelGGL((gemm128<1>), dim3(16, 32, 1), dim3(256), 0, stream, hnorm, wbf_in, (void*)z,
                     (const unsigned short*)nullptr, 1024, 1024, 1024, 2048, 0LL, 0LL, 0LL);
  hipLaunchKernelGGL((gemm128<1>), dim3(18, 32, 1), dim3(256), 0, stream, hnorm,
                     wbf_in + 2048 * 1024, (void*)xraw, (const unsigned short*)nullptr, 1024, 1024,
                     1024, 2304, 0LL, 0LL, 0LL);
  hipLaunchKernelGGL((gemm_small_nt<4>), dim3(1, 16, 1), dim3(256), 0, stream, hnorm,
                     wbf_in + 4352 * 1024, dtraw, M, 32, 1024, 1024, 1024, 32);
  // s4: conv + silu -> xBC bf16
  hipLaunchKernelGGL(conv_silu_k, dim3(M), dim3(256), 0, stream, xraw, w_conv, b_conv, xBC);
  // s4b: w_out conversion
  hipLaunchKernelGGL(f32_to_bf16_k, dim3(2048), dim3(256), 0, stream, w_out, wbf_out, 524288LL);
  // s5: dt softplus
  hipLaunchKernelGGL(dt_softplus_k, dim3(512), dim3(256), 0, stream, dtraw, dt_bias, dt_s);
  // s6: dA cumsum
  hipLaunchKernelGGL(dA_cumsum_k, dim3(1024), dim3(128), 0, stream, dt_s, A_log, dA_cs);
  // s7: G = C @ B^T per chunk, stored bf16
  hipLaunchKernelGGL((gemm128<1>), dim3(1, 1, 32), dim3(256), 0, stream, xBC + 2176, xBC + 2048,
                     (void*)Gbuf, (const unsigned short*)nullptr, 128, 2304, 2304, 128, 294912LL,
                     294912LL, 16384LL);
  // s8: Y_diag + local states (MFMA)
  hipLaunchKernelGGL(ssd_diag_states_k, dim3(1024), dim3(256), 0, stream, xBC, dt_s, dA_cs, Gbuf,
                     ybuf, states);
  // s9: inter-chunk scan
  hipLaunchKernelGGL(ssd_scan_k, dim3(64), dim3(256), 0, stream, dA_cs, states);
  // s10: Y_off + D-skip (MFMA)
  hipLaunchKernelGGL(ssd_off_k, dim3(1024), dim3(256), 0, stream, xBC, dA_cs, states, Dvec, ybuf);
  // s11: gated rmsnorm -> ygn bf16
  hipLaunchKernelGGL(gated_rmsnorm2048_k, dim3(M), dim3(256), 0, stream, ybuf, z, w_mnorm, ygn,
                     1e-5f);
  // s12: out_proj -> outtmp fp32
  hipLaunchKernelGGL((gemm128<0>), dim3(8, 32, 1), dim3(256), 0, stream, ygn, wbf_out,
                     (void*)outtmp, (const unsigned short*)nullptr, 2048, 2048, 2048, 1024, 0LL,
                     0LL, 0LL);
  // s13: residual add -> mh
  hipLaunchKernelGGL(add_f32_k, dim3(4096), dim3(256), 0, stream, hs, outtmp, mh, 1048576LL);
  // s14: rmsnorm(ln2) -> h2 bf16
  hipLaunchKernelGGL(rmsnorm1024_bf16_k, dim3(M), dim3(256), 0, stream, mh, w_ln2, h2, 1e-6f);
  // s15: up -> upo bf16
  hipLaunchKernelGGL((gemm128<1>), dim3(32, 32, 1), dim3(256), 0, stream, h2, wbf_up, (void*)upo,
                     (const unsigned short*)nullptr, 1024, 1024, 1024, 4096, 0LL, 0LL, 0LL);
  // s16: gate with fused swiglu -> act bf16
  hipLaunchKernelGGL((gemm128<2>), dim3(32, 32, 1), dim3(256), 0, stream, h2, wbf_gate, (void*)act,
                     upo, 1024, 1024, 1024, 4096, 0LL, 0LL, 0LL);
  // s17: down -> downtmp fp32
  hipLaunchKernelGGL((gemm128<0>), dim3(8, 32, 1), dim3(256), 0, stream, act, wbf_down,
                     (void*)downtmp, (const unsigned short*)nullptr, 4096, 4096, 4096, 1024, 0LL,
                     0LL, 0LL);
  // s18: final residual add -> out
  hipLaunchKernelGGL(add_f32_k, dim3(4096), dim3(256), 0, stream, mh, downtmp, out, 1048576LL);
}

// Round 5
// 613.947 us; speedup vs baseline: 1.8080x; 1.0975x over previous
//
#include <hip/hip_runtime.h>

#define DEV static __device__ __forceinline__

typedef short bf16x8 __attribute__((ext_vector_type(8)));
typedef float floatx4 __attribute__((ext_vector_type(4)));
typedef unsigned short ushort4v __attribute__((ext_vector_type(4)));
typedef unsigned short ushort8v __attribute__((ext_vector_type(8)));

DEV unsigned short f32_bf16(float f) {
  unsigned int u = __builtin_bit_cast(unsigned int, f);
  u = u + 0x7fffu + ((u >> 16) & 1u);
  return (unsigned short)(u >> 16);
}
DEV float bf2f(unsigned short u) {
  unsigned int v = ((unsigned int)u) << 16;
  return __builtin_bit_cast(float, v);
}
DEV float sigmoidf_(float x) { return 1.0f / (1.0f + __expf(-x)); }
DEV float siluf_(float x) { return x * sigmoidf_(x); }

#define GLD_LDS16(g, l)                                                              \
  __builtin_amdgcn_global_load_lds((const __attribute__((address_space(1))) void*)(g), \
                                   (__attribute__((address_space(3))) void*)(l), 16, 0, 0)

// ---------------------------------------------------------------------------
// m97-style MFMA GEMM: C[M,N] = A[M,K] @ B[N,K]^T, bf16 in, 128x128 block tile,
// BK=32, LDS staging via global_load_lds(16B), XOR-swizzled k-chunks, GM=4
// supertile block swizzle for L2. Split-K via blockIdx.z: pass K=Ksub,
// bsA=bsB=Ksub (element offset), bsC=M*N (partial-buffer stride).
// MODE 0: fp32 store. 1: bf16. 2: bf16(silu(acc)*other).
// ---------------------------------------------------------------------------
template <int MODE>
__global__ __launch_bounds__(256) void gemm128(
    const unsigned short* __restrict__ A, const unsigned short* __restrict__ B,
    void* __restrict__ Cv, const unsigned short* __restrict__ other,
    int K, int lda, int ldb, int ldc, long long bsA, long long bsB, long long bsC) {
  __shared__ unsigned short As[128 * 32];
  __shared__ unsigned short Bs[128 * 32];
  A += (long long)blockIdx.z * bsA;
  B += (long long)blockIdx.z * bsB;
  const long long coff = (long long)blockIdx.z * bsC;
  const int tid = threadIdx.x;
  const int w = tid >> 6, lane = tid & 63;

  // GM=4 supertile swizzle (cutlass-style): consecutive blocks walk M within
  // a 4-row group, then N; improves B-tile temporal locality in L2.
  const int nbx = gridDim.x, nby = gridDim.y;
  const int GM = 4;
  int bid = blockIdx.y * nbx + blockIdx.x;
  int gid = bid / (GM * nbx);
  int rem = bid - gid * (GM * nbx);
  int gsz = min(GM, nby - gid * GM);
  int mtile = gid * GM + rem % gsz;
  int ntile = rem / gsz;
  const int m0 = mtile << 7, n0 = ntile << 7;

  const int srow = lane >> 2;
  const int schunk = ((lane & 3) ^ (srow & 3)) * 8;
  const unsigned short* ag0 = A + (long long)(m0 + w * 32 + srow) * lda + schunk;
  const unsigned short* ag1 = ag0 + (long long)16 * lda;
  const unsigned short* bg0 = B + (long long)(n0 + w * 32 + srow) * ldb + schunk;
  const unsigned short* bg1 = bg0 + (long long)16 * ldb;
  unsigned short* al0 = As + (w * 32) * 32 + lane * 8;
  unsigned short* al1 = As + (w * 32 + 16) * 32 + lane * 8;
  unsigned short* bl0 = Bs + (w * 32) * 32 + lane * 8;
  unsigned short* bl1 = Bs + (w * 32 + 16) * 32 + lane * 8;

  const int wr = (w >> 1) << 6, wc = (w & 1) << 6;
  const int fr = lane & 15;
  const int slot = (((lane >> 4) ^ (fr & 3))) << 3;

  floatx4 acc[4][4];
#pragma unroll
  for (int i = 0; i < 4; ++i)
#pragma unroll
    for (int j = 0; j < 4; ++j) acc[i][j] = (floatx4){0.f, 0.f, 0.f, 0.f};

  for (int k0 = 0; k0 < K; k0 += 32) {
    __syncthreads();
    GLD_LDS16(ag0 + k0, al0);
    GLD_LDS16(ag1 + k0, al1);
    GLD_LDS16(bg0 + k0, bl0);
    GLD_LDS16(bg1 + k0, bl1);
    __syncthreads();
    bf16x8 af[4], bf_[4];
#pragma unroll
    for (int i = 0; i < 4; ++i)
      af[i] = *(const bf16x8*)(As + (wr + i * 16 + fr) * 32 + slot);
#pragma unroll
    for (int j = 0; j < 4; ++j)
      bf_[j] = *(const bf16x8*)(Bs + (wc + j * 16 + fr) * 32 + slot);
#pragma unroll
    for (int i = 0; i < 4; ++i)
#pragma unroll
      for (int j = 0; j < 4; ++j)
        acc[i][j] = __builtin_amdgcn_mfma_f32_16x16x32_bf16(af[i], bf_[j], acc[i][j], 0, 0, 0);
  }

  const int r0 = (lane >> 4) << 2;
#pragma unroll
  for (int i = 0; i < 4; ++i) {
#pragma unroll
    for (int j = 0; j < 4; ++j) {
      long long base = (long long)(m0 + wr + i * 16 + r0) * ldc + (n0 + wc + j * 16 + fr);
#pragma unroll
      for (int r = 0; r < 4; ++r) {
        long long idx = coff + base + (long long)r * ldc;
        float v = acc[i][j][r];
        if constexpr (MODE == 0) {
          ((float*)Cv)[idx] = v;
        } else if constexpr (MODE == 1) {
          ((unsigned short*)Cv)[idx] = f32_bf16(v);
        } else {
          ((unsigned short*)Cv)[idx] = f32_bf16(siluf_(v) * bf2f(other[idx]));
        }
      }
    }
  }
}

// ---------------------------------------------------------------------------
// small GEMM (direct-from-global), used only for the N=32 dt projection.
// ---------------------------------------------------------------------------
template <int WM>
__global__ __launch_bounds__(256) void gemm_small_nt(
    const unsigned short* __restrict__ A, const unsigned short* __restrict__ B,
    float* __restrict__ C, int M, int N, int K, int lda, int ldb, int ldc) {
  const int w = threadIdx.x >> 6;
  const int lane = threadIdx.x & 63;
  const int lm = lane & 15;
  const int ko = (lane >> 4) << 3;
  const int bn0 = blockIdx.x << 6;
  const int m_base = blockIdx.y * (WM * 64) + w * (WM * 16);

  const unsigned short* arow[WM];
#pragma unroll
  for (int i = 0; i < WM; ++i) arow[i] = A + (long long)(m_base + i * 16 + lm) * lda + ko;
  int nv = (N - bn0) >> 4;
  nv = nv > 4 ? 4 : nv;
  const unsigned short* brow[4];
#pragma unroll
  for (int j = 0; j < 4; ++j) {
    int nr = bn0 + j * 16 + lm;
    brow[j] = B + (long long)(j < nv ? nr : 0) * ldb + ko;
  }
  floatx4 acc[WM][4];
#pragma unroll
  for (int i = 0; i < WM; ++i)
#pragma unroll
    for (int j = 0; j < 4; ++j) acc[i][j] = (floatx4){0.f, 0.f, 0.f, 0.f};
  for (int k0 = 0; k0 < K; k0 += 32) {
    bf16x8 a[WM];
#pragma unroll
    for (int i = 0; i < WM; ++i) a[i] = *(const bf16x8*)(arow[i] + k0);
#pragma unroll
    for (int j = 0; j < 4; ++j) {
      if (j < nv) {
        bf16x8 b = *(const bf16x8*)(brow[j] + k0);
#pragma unroll
        for (int i = 0; i < WM; ++i)
          acc[i][j] = __builtin_amdgcn_mfma_f32_16x16x32_bf16(a[i], b, acc[i][j], 0, 0, 0);
      }
    }
  }
  const int r0 = (lane >> 4) << 2;
#pragma unroll
  for (int i = 0; i < WM; ++i)
#pragma unroll
    for (int j = 0; j < 4; ++j)
      if (j < nv) {
        int col = bn0 + j * 16 + lm;
        long long base = (long long)(m_base + i * 16 + r0) * ldc + col;
#pragma unroll
        for (int r = 0; r < 4; ++r) C[base + (long long)r * ldc] = acc[i][j][r];
      }
}

// ---------------------------------------------------------------------------
__global__ __launch_bounds__(256) void f32_to_bf16_k(const float* __restrict__ src,
                                                     unsigned short* __restrict__ dst,
                                                     long long n4) {
  long long i = (long long)blockIdx.x * 256 + threadIdx.x;
  if (i < n4) {
    float4 v = ((const float4*)src)[i];
    ushort4v o = {f32_bf16(v.x), f32_bf16(v.y), f32_bf16(v.z), f32_bf16(v.w)};
    ((ushort4v*)dst)[i] = o;
  }
}

__global__ __launch_bounds__(256) void zero_out_k(float* __restrict__ o, long long n) {
  long long i = (long long)blockIdx.x * 256 + threadIdx.x;
  if (i < n) o[i] = 0.f;
}

// ---------------------------------------------------------------------------
__global__ __launch_bounds__(256) void rmsnorm1024_bf16_k(const float* __restrict__ x,
                                                          const float* __restrict__ w,
                                                          unsigned short* __restrict__ out,
                                                          float eps) {
  long long row = blockIdx.x;
  int t = threadIdx.x;
  float4 v = ((const float4*)(x + row * 1024))[t];
  float ss = v.x * v.x + v.y * v.y + v.z * v.z + v.w * v.w;
  __shared__ float red[4];
#pragma unroll
  for (int o = 32; o > 0; o >>= 1) ss += __shfl_down(ss, o, 64);
  if ((t & 63) == 0) red[t >> 6] = ss;
  __syncthreads();
  float tot = red[0] + red[1] + red[2] + red[3];
  float sc = rsqrtf(tot * (1.0f / 1024.0f) + eps);
  float4 wv = ((const float4*)w)[t];
  ushort4v o = {f32_bf16(v.x * sc * wv.x), f32_bf16(v.y * sc * wv.y),
                f32_bf16(v.z * sc * wv.z), f32_bf16(v.w * sc * wv.w)};
  ((ushort4v*)(out + row * 1024))[t] = o;
}

// ---------------------------------------------------------------------------
// Fused: mh = hs + sum_{p<np} parts[p]; h2 = bf16(rmsnorm(mh) * w). 1024 cols.
// ---------------------------------------------------------------------------
__global__ __launch_bounds__(256) void add_rmsnorm_k(const float* __restrict__ hs,
                                                     const float* __restrict__ parts,
                                                     long long pstride, int np,
                                                     const float* __restrict__ w,
                                                     float* __restrict__ mh,
                                                     unsigned short* __restrict__ h2, float eps) {
  long long row = blockIdx.x;
  int t = threadIdx.x;
  float4 v = ((const float4*)(hs + row * 1024))[t];
  for (int p = 0; p < np; ++p) {
    float4 u = ((const float4*)(parts + p * pstride + row * 1024))[t];
    v.x += u.x;
    v.y += u.y;
    v.z += u.z;
    v.w += u.w;
  }
  ((float4*)(mh + row * 1024))[t] = v;
  float ss = v.x * v.x + v.y * v.y + v.z * v.z + v.w * v.w;
  __shared__ float red[4];
#pragma unroll
  for (int o = 32; o > 0; o >>= 1) ss += __shfl_down(ss, o, 64);
  if ((t & 63) == 0) red[t >> 6] = ss;
  __syncthreads();
  float tot = red[0] + red[1] + red[2] + red[3];
  float sc = rsqrtf(tot * (1.0f / 1024.0f) + eps);
  float4 wv = ((const float4*)w)[t];
  ushort4v o = {f32_bf16(v.x * sc * wv.x), f32_bf16(v.y * sc * wv.y),
                f32_bf16(v.z * sc * wv.z), f32_bf16(v.w * sc * wv.w)};
  ((ushort4v*)(h2 + row * 1024))[t] = o;
}

// ---------------------------------------------------------------------------
// o = a + sum_{p<np} parts[p]   (float4)
// ---------------------------------------------------------------------------
__global__ __launch_bounds__(256) void addn_f32_k(const float* __restrict__ a,
                                                  const float* __restrict__ parts,
                                                  long long pstride, int np,
                                                  float* __restrict__ o, long long n4) {
  long long i = (long long)blockIdx.x * 256 + threadIdx.x;
  if (i < n4) {
    float4 x = ((const float4*)a)[i];
    for (int p = 0; p < np; ++p) {
      float4 u = ((const float4*)(parts + p * pstride))[i];
      x.x += u.x;
      x.y += u.y;
      x.z += u.z;
      x.w += u.w;
    }
    ((float4*)o)[i] = x;
  }
}

// ---------------------------------------------------------------------------
__global__ __launch_bounds__(256) void gated_rmsnorm2048_k(const unsigned short* __restrict__ y,
                                                           const unsigned short* __restrict__ z,
                                                           const float* __restrict__ w,
                                                           unsigned short* __restrict__ out,
                                                           float eps) {
  long long row = blockIdx.x;
  int t = threadIdx.x;
  ushort8v yv = ((const ushort8v*)(y + row * 2048))[t];
  ushort8v zv = ((const ushort8v*)(z + row * 2048))[t];
  float g[8];
  float ss = 0.f;
#pragma unroll
  for (int j = 0; j < 8; ++j) {
    g[j] = bf2f(yv[j]) * siluf_(bf2f(zv[j]));
    ss += g[j] * g[j];
  }
  __shared__ float red[4];
#pragma unroll
  for (int o = 32; o > 0; o >>= 1) ss += __shfl_down(ss, o, 64);
  if ((t & 63) == 0) red[t >> 6] = ss;
  __syncthreads();
  float tot = red[0] + red[1] + red[2] + red[3];
  float sc = rsqrtf(tot * (1.0f / 2048.0f) + eps);
  float ww[8];
  *(float4*)&ww[0] = ((const float4*)w)[2 * t];
  *(float4*)&ww[4] = ((const float4*)w)[2 * t + 1];
  ushort8v o;
#pragma unroll
  for (int j = 0; j < 8; ++j) o[j] = f32_bf16(g[j] * sc * ww[j]);
  ((ushort8v*)(out + row * 2048))[t] = o;
}

// ---------------------------------------------------------------------------
__global__ __launch_bounds__(256) void conv_silu_k(const unsigned short* __restrict__ xraw,
                                                   const float* __restrict__ wconv,
                                                   const float* __restrict__ bconv,
                                                   unsigned short* __restrict__ xBC) {
  int m = blockIdx.x;
  int l = m & 2047;
  for (int ch = threadIdx.x; ch < 2304; ch += 256) {
    float acc = bconv[ch];
#pragma unroll
    for (int k = 0; k < 4; ++k) {
      int lk = l + k - 3;
      if (lk >= 0) acc += bf2f(xraw[(long long)(m + k - 3) * 2304 + ch]) * wconv[ch * 4 + k];
    }
    xBC[(long long)m * 2304 + ch] = f32_bf16(siluf_(acc));
  }
}

// ---------------------------------------------------------------------------
__global__ __launch_bounds__(256) void dt_softplus_k(const float* __restrict__ dtraw,
                                                     const float* __restrict__ dt_bias,
                                                     float* __restrict__ dt_s) {
  int i = blockIdx.x * 256 + threadIdx.x;
  float xv = dtraw[i] + dt_bias[i & 31];
  dt_s[i] = xv > 20.f ? xv : log1pf(expf(xv));
}

// ---------------------------------------------------------------------------
__global__ __launch_bounds__(128) void dA_cumsum_k(const float* __restrict__ dt_s,
                                                   const float* __restrict__ A_log,
                                                   float* __restrict__ dA_cs) {
  int bi = blockIdx.x;
  int c = bi & 15, h = (bi >> 4) & 31, b = bi >> 9;
  int q = threadIdx.x;
  float A = -expf(A_log[h]);
  float v = dt_s[((long long)(b * 2048 + c * 128 + q)) * 32 + h] * A;
  __shared__ float sbuf[128];
  sbuf[q] = v;
  __syncthreads();
  for (int off = 1; off < 128; off <<= 1) {
    float tv = (q >= off) ? sbuf[q - off] : 0.f;
    __syncthreads();
    sbuf[q] += tv;
    __syncthreads();
  }
  dA_cs[(long long)bi * 128 + q] = sbuf[q];
}

// ---------------------------------------------------------------------------
// S3 (MFMA): Y_diag -> y bf16, local states -> states bf16.
// ---------------------------------------------------------------------------
__global__ __launch_bounds__(256) void ssd_diag_states_k(
    const unsigned short* __restrict__ xBC, const float* __restrict__ dt_s,
    const float* __restrict__ dA_cs, const unsigned short* __restrict__ G,
    unsigned short* __restrict__ y, unsigned short* __restrict__ states) {
  __shared__ unsigned short Mz[128 * 136];
  __shared__ unsigned short xdT[64 * 136];
  __shared__ float Acs[128];
  __shared__ float wdec[128];
  const int bx = blockIdx.x;
  const int h = bx & 31, c = (bx >> 5) & 15, b = bx >> 9;
  const int t = threadIdx.x;
  const int w = t >> 6, lane = t & 63, fr = lane & 15, hi = lane >> 4;
  const long long rowbase = (long long)b * 2048 + c * 128;
  const long long abase = ((long long)((b * 32 + h) * 16 + c)) << 7;

  if (t < 128) {
    float a = dA_cs[abase + t];
    Acs[t] = a;
    wdec[t] = __expf(dA_cs[abase + 127] - a);
  }
  {
    int s = t >> 1, p0 = (t & 1) * 32;
    float dtv = dt_s[(rowbase + s) * 32 + h];
    const ushort8v* xv = (const ushort8v*)(xBC + (rowbase + s) * 2304 + h * 64 + p0);
#pragma unroll
    for (int i = 0; i < 4; ++i) {
      ushort8v vv = xv[i];
#pragma unroll
      for (int j = 0; j < 8; ++j) xdT[(p0 + i * 8 + j) * 136 + s] = f32_bf16(bf2f(vv[j]) * dtv);
    }
  }
  __syncthreads();
  {
    int q = t >> 1, s0 = (t & 1) * 64;
    float aq = Acs[q];
    const ushort8v* gv =
        (const ushort8v*)(G + (((long long)(b * 16 + c)) * 128 + q) * 128 + s0);
#pragma unroll
    for (int i = 0; i < 8; ++i) {
      ushort8v gg = gv[i];
#pragma unroll
      for (int j = 0; j < 8; ++j) {
        int s = s0 + i * 8 + j;
        float m = (s <= q) ? bf2f(gg[j]) * __expf(aq - Acs[s]) : 0.f;
        Mz[q * 136 + s] = f32_bf16(m);
      }
    }
  }
  __syncthreads();
  const int q0 = w << 5;
  {
    floatx4 acc[2][4];
#pragma unroll
    for (int i = 0; i < 2; ++i)
#pragma unroll
      for (int j = 0; j < 4; ++j) acc[i][j] = (floatx4){0.f, 0.f, 0.f, 0.f};
#pragma unroll
    for (int k0 = 0; k0 < 128; k0 += 32) {
      int kk = k0 + hi * 8;
      bf16x8 a0 = *(const bf16x8*)(Mz + (q0 + fr) * 136 + kk);
      bf16x8 a1 = *(const bf16x8*)(Mz + (q0 + 16 + fr) * 136 + kk);
      bf16x8 bf_[4];
#pragma unroll
      for (int j = 0; j < 4; ++j) bf_[j] = *(const bf16x8*)(xdT + (j * 16 + fr) * 136 + kk);
#pragma unroll
      for (int j = 0; j < 4; ++j) {
        acc[0][j] = __builtin_amdgcn_mfma_f32_16x16x32_bf16(a0, bf_[j], acc[0][j], 0, 0, 0);
        acc[1][j] = __builtin_amdgcn_mfma_f32_16x16x32_bf16(a1, bf_[j], acc[1][j], 0, 0, 0);
      }
    }
#pragma unroll
    for (int i = 0; i < 2; ++i)
#pragma unroll
      for (int r = 0; r < 4; ++r) {
        int q = q0 + i * 16 + hi * 4 + r;
        unsigned short* yrow = y + (rowbase + q) * 2048 + h * 64;
#pragma unroll
        for (int j = 0; j < 4; ++j) yrow[j * 16 + fr] = f32_bf16(acc[i][j][r]);
      }
  }
  __syncthreads();
  {
    int s = t >> 1, n0 = (t & 1) * 64;
    float wd = wdec[s];
    const ushort8v* bv = (const ushort8v*)(xBC + (rowbase + s) * 2304 + 2048 + n0);
#pragma unroll
    for (int i = 0; i < 8; ++i) {
      ushort8v bb = bv[i];
#pragma unroll
      for (int j = 0; j < 8; ++j) Mz[(n0 + i * 8 + j) * 136 + s] = f32_bf16(bf2f(bb[j]) * wd);
    }
  }
  __syncthreads();
  {
    floatx4 acc[2][4];
#pragma unroll
    for (int i = 0; i < 2; ++i)
#pragma unroll
      for (int j = 0; j < 4; ++j) acc[i][j] = (floatx4){0.f, 0.f, 0.f, 0.f};
#pragma unroll
    for (int k0 = 0; k0 < 128; k0 += 32) {
      int kk = k0 + hi * 8;
      bf16x8 a0 = *(const bf16x8*)(Mz + (q0 + fr) * 136 + kk);
      bf16x8 a1 = *(const bf16x8*)(Mz + (q0 + 16 + fr) * 136 + kk);
      bf16x8 bf_[4];
#pragma unroll
      for (int j = 0; j < 4; ++j) bf_[j] = *(const bf16x8*)(xdT + (j * 16 + fr) * 136 + kk);
#pragma unroll
      for (int j = 0; j < 4; ++j) {
        acc[0][j] = __builtin_amdgcn_mfma_f32_16x16x32_bf16(a0, bf_[j], acc[0][j], 0, 0, 0);
        acc[1][j] = __builtin_amdgcn_mfma_f32_16x16x32_bf16(a1, bf_[j], acc[1][j], 0, 0, 0);
      }
    }
    unsigned short* st = states + (long long)bx * 8192;
#pragma unroll
    for (int i = 0; i < 2; ++i)
#pragma unroll
      for (int j = 0; j < 4; ++j) {
        int p = j * 16 + fr;
        int n = q0 + i * 16 + hi * 4;
        ushort4v o;
#pragma unroll
        for (int r = 0; r < 4; ++r) o[r] = f32_bf16(acc[i][j][r]);
        *(ushort4v*)(st + p * 128 + n) = o;
      }
  }
}

// ---------------------------------------------------------------------------
__global__ __launch_bounds__(256) void ssd_scan_k(const float* __restrict__ dA_cs,
                                                  unsigned short* __restrict__ states) {
  int h = blockIdx.x & 31, b = blockIdx.x >> 5;
  int t = threadIdx.x;
  float carry[32];
#pragma unroll
  for (int i = 0; i < 32; ++i) carry[i] = 0.f;
  for (int c = 0; c < 16; ++c) {
    long long base = ((long long)((b * 16 + c) * 32 + h)) * 8192;
    float dec = __expf(dA_cs[(((long long)((b * 32 + h) * 16 + c)) << 7) + 127]);
#pragma unroll
    for (int i = 0; i < 32; ++i) {
      long long idx = base + t + i * 256;
      float local = bf2f(states[idx]);
      states[idx] = f32_bf16(carry[i]);
      carry[i] = dec * carry[i] + local;
    }
  }
}

// ---------------------------------------------------------------------------
__global__ __launch_bounds__(256) void ssd_off_k(const unsigned short* __restrict__ xBC,
                                                 const float* __restrict__ dA_cs,
                                                 const unsigned short* __restrict__ states,
                                                 const float* __restrict__ Dvec,
                                                 unsigned short* __restrict__ y) {
  __shared__ float eA[128];
  const int bx = blockIdx.x;
  const int h = bx & 31, c = (bx >> 5) & 15, b = bx >> 9;
  const int t = threadIdx.x;
  const int w = t >> 6, lane = t & 63, fr = lane & 15, hi = lane >> 4;
  const long long rowbase = (long long)b * 2048 + c * 128;
  const long long abase = ((long long)((b * 32 + h) * 16 + c)) << 7;
  if (t < 128) eA[t] = __expf(dA_cs[abase + t]);
  __syncthreads();

  const unsigned short* st = states + (long long)bx * 8192;
  const int q0 = w << 5;
  floatx4 acc[2][4];
#pragma unroll
  for (int i = 0; i < 2; ++i)
#pragma unroll
    for (int j = 0; j < 4; ++j) acc[i][j] = (floatx4){0.f, 0.f, 0.f, 0.f};

#pragma unroll
  for (int k0 = 0; k0 < 128; k0 += 32) {
    int kk = k0 + hi * 8;
    bf16x8 a0 = *(const bf16x8*)(xBC + (rowbase + q0 + fr) * 2304 + 2176 + kk);
    bf16x8 a1 = *(const bf16x8*)(xBC + (rowbase + q0 + 16 + fr) * 2304 + 2176 + kk);
    bf16x8 bf_[4];
#pragma unroll
    for (int j = 0; j < 4; ++j) bf_[j] = *(const bf16x8*)(st + (j * 16 + fr) * 128 + kk);
#pragma unroll
    for (int j = 0; j < 4; ++j) {
      acc[0][j] = __builtin_amdgcn_mfma_f32_16x16x32_bf16(a0, bf_[j], acc[0][j], 0, 0, 0);
      acc[1][j] = __builtin_amdgcn_mfma_f32_16x16x32_bf16(a1, bf_[j], acc[1][j], 0, 0, 0);
    }
  }

  float Dh = Dvec[h];
#pragma unroll
  for (int i = 0; i < 2; ++i) {
#pragma unroll
    for (int r = 0; r < 4; ++r) {
      int q = q0 + i * 16 + hi * 4 + r;
      float e = eA[q];
      const unsigned short* xrow = xBC + (rowbase + q) * 2304 + h * 64;
      unsigned short* yrow = y + (rowbase + q) * 2048 + h * 64;
#pragma unroll
      for (int j = 0; j < 4; ++j) {
        int p = j * 16 + fr;
        float v = bf2f(yrow[p]) + e * acc[i][j][r] + Dh * bf2f(xrow[p]);
        yrow[p] = f32_bf16(v);
      }
    }
  }
}

// ---------------------------------------------------------------------------
extern "C" void kernel_launch(void* const* d_in, const int* in_sizes, int n_in, void* d_out,
                              int out_size, void* d_ws, size_t ws_size, hipStream_t stream) {
  const float* hs = (const float*)d_in[0];
  const float* w_ln1 = (const float*)d_in[1];
  const float* w_in = (const float*)d_in[2];
  const float* w_conv = (const float*)d_in[3];
  const float* b_conv = (const float*)d_in[4];
  const float* dt_bias = (const float*)d_in[5];
  const float* A_log = (const float*)d_in[6];
  const float* Dvec = (const float*)d_in[7];
  const float* w_mnorm = (const float*)d_in[8];
  const float* w_out = (const float*)d_in[9];
  const float* w_ln2 = (const float*)d_in[10];
  const float* w_gate = (const float*)d_in[11];
  const float* w_up = (const float*)d_in[12];
  const float* w_down = (const float*)d_in[13];
  float* out = (float*)d_out;
  const int M = 4096;

  char* ws = (char*)d_ws;
  const size_t R0 = 0;               // z bf16 -> outproj partials (with R1) -> act bf16
  const size_t R1 = 33554432;        // xraw bf16 -> states+y bf16 -> partials -> upo -> down partials
  const size_t R1b = R1 + 33554432;  // wbf_out
  const size_t R2 = 71303168;        // xBC bf16 -> ygn -> h2
  const size_t R3 = 90177536;        // hnorm+wbf_in -> dt_s/dA/G -> mh
  const size_t R4 = 107544576;       // dtraw fp32
  const size_t W0 = 108068864;       // wbf_gate | wbf_up | wbf_down
  const size_t NEED = 133234688;

  if (ws_size < NEED) {
    hipLaunchKernelGGL(zero_out_k, dim3((out_size + 255) / 256), dim3(256), 0, stream, out,
                       (long long)out_size);
    return;
  }

  unsigned short* z = (unsigned short*)(ws + R0);
  unsigned short* act = (unsigned short*)(ws + R0);
  float* oproj_parts = (float*)(ws + R0);  // 4 x 16 MB, spans R0+R1 (both dead at s12)
  unsigned short* xraw = (unsigned short*)(ws + R1);
  unsigned short* states = (unsigned short*)(ws + R1);
  unsigned short* ybuf = (unsigned short*)(ws + R1 + 16777216);
  unsigned short* upo = (unsigned short*)(ws + R1);
  float* down_parts = (float*)(ws + R1);  // 2 x 16 MB (act in R0 stays live)
  unsigned short* wbf_out = (unsigned short*)(ws + R1b);
  unsigned short* xBC = (unsigned short*)(ws + R2);
  unsigned short* ygn = (unsigned short*)(ws + R2);
  unsigned short* h2 = (unsigned short*)(ws + R2);
  unsigned short* hnorm = (unsigned short*)(ws + R3);
  unsigned short* wbf_in = (unsigned short*)(ws + R3 + 8388608);
  float* dt_s = (float*)(ws + R3);
  float* dA_cs = (float*)(ws + R3 + 524288);
  unsigned short* Gbuf = (unsigned short*)(ws + R3 + 1048576);
  float* mh = (float*)(ws + R3);
  float* dtraw = (float*)(ws + R4);
  unsigned short* wbf_gate = (unsigned short*)(ws + W0);
  unsigned short* wbf_up = (unsigned short*)(ws + W0 + 8388608);
  unsigned short* wbf_down = (unsigned short*)(ws + W0 + 16777216);

  // s1: rmsnorm(ln1) -> hnorm bf16
  hipLaunchKernelGGL(rmsnorm1024_bf16_k, dim3(M), dim3(256), 0, stream, hs, w_ln1, hnorm, 1e-6f);
  // s2: weight conversions
  hipLaunchKernelGGL(f32_to_bf16_k, dim3(4384), dim3(256), 0, stream, w_in, wbf_in, 1122304LL);
  hipLaunchKernelGGL(f32_to_bf16_k, dim3(4096), dim3(256), 0, stream, w_gate, wbf_gate, 1048576LL);
  hipLaunchKernelGGL(f32_to_bf16_k, dim3(4096), dim3(256), 0, stream, w_up, wbf_up, 1048576LL);
  hipLaunchKernelGGL(f32_to_bf16_k, dim3(4096), dim3(256), 0, stream, w_down, wbf_down, 1048576LL);
  // s3: in_proj -> z bf16 / xraw bf16 / dtraw fp32
  hipLaunchKernelGGL((gemm128<1>), dim3(16, 32, 1), dim3(256), 0, stream, hnorm, wbf_in, (void*)z,
                     (const unsigned short*)nullptr, 1024, 1024, 1024, 2048, 0LL, 0LL, 0LL);
  hipLaunchKernelGGL((gemm128<1>), dim3(18, 32, 1), dim3(256), 0, stream, hnorm,
                     wbf_in + 2048 * 1024, (void*)xraw, (const unsigned short*)nullptr, 1024, 1024,
                     1024, 2304, 0LL, 0LL, 0LL);
  hipLaunchKernelGGL((gemm_small_nt<4>), dim3(1, 16, 1), dim3(256), 0, stream, hnorm,
                     wbf_in + 4352 * 1024, dtraw, M, 32, 1024, 1024, 1024, 32);
  // s4: conv + silu -> xBC bf16
  hipLaunchKernelGGL(conv_silu_k, dim3(M), dim3(256), 0, stream, xraw, w_conv, b_conv, xBC);
  // s4b: w_out conversion
  hipLaunchKernelGGL(f32_to_bf16_k, dim3(2048), dim3(256), 0, stream, w_out, wbf_out, 524288LL);
  // s5: dt softplus
  hipLaunchKernelGGL(dt_softplus_k, dim3(512), dim3(256), 0, stream, dtraw, dt_bias, dt_s);
  // s6: dA cumsum
  hipLaunchKernelGGL(dA_cumsum_k, dim3(1024), dim3(128), 0, stream, dt_s, A_log, dA_cs);
  // s7: G = C @ B^T per chunk, stored bf16
  hipLaunchKernelGGL((gemm128<1>), dim3(1, 1, 32), dim3(256), 0, stream, xBC + 2176, xBC + 2048,
                     (void*)Gbuf, (const unsigned short*)nullptr, 128, 2304, 2304, 128, 294912LL,
                     294912LL, 16384LL);
  // s8: Y_diag + local states (MFMA)
  hipLaunchKernelGGL(ssd_diag_states_k, dim3(1024), dim3(256), 0, stream, xBC, dt_s, dA_cs, Gbuf,
                     ybuf, states);
  // s9: inter-chunk scan
  hipLaunchKernelGGL(ssd_scan_k, dim3(64), dim3(256), 0, stream, dA_cs, states);
  // s10: Y_off + D-skip (MFMA)
  hipLaunchKernelGGL(ssd_off_k, dim3(1024), dim3(256), 0, stream, xBC, dA_cs, states, Dvec, ybuf);
  // s11: gated rmsnorm -> ygn bf16
  hipLaunchKernelGGL(gated_rmsnorm2048_k, dim3(M), dim3(256), 0, stream, ybuf, z, w_mnorm, ygn,
                     1e-5f);
  // s12: out_proj, split-K=4 -> 4 fp32 partials (z/states/y all dead)
  hipLaunchKernelGGL((gemm128<0>), dim3(8, 32, 4), dim3(256), 0, stream, ygn, wbf_out,
                     (void*)oproj_parts, (const unsigned short*)nullptr, 512, 2048, 2048, 1024,
                     512LL, 512LL, 4194304LL);
  // s13: mh = hs + sum(partials); h2 = rmsnorm(mh, ln2)  [fused]
  hipLaunchKernelGGL(add_rmsnorm_k, dim3(M), dim3(256), 0, stream, hs, oproj_parts, 4194304LL, 4,
                     w_ln2, mh, h2, 1e-6f);
  // s15: up -> upo bf16
  hipLaunchKernelGGL((gemm128<1>), dim3(32, 32, 1), dim3(256), 0, stream, h2, wbf_up, (void*)upo,
                     (const unsigned short*)nullptr, 1024, 1024, 1024, 4096, 0LL, 0LL, 0LL);
  // s16: gate with fused swiglu -> act bf16
  hipLaunchKernelGGL((gemm128<2>), dim3(32, 32, 1), dim3(256), 0, stream, h2, wbf_gate, (void*)act,
                     upo, 1024, 1024, 1024, 4096, 0LL, 0LL, 0LL);
  // s17: down, split-K=2 -> 2 fp32 partials in R1 (act in R0 stays live)
  hipLaunchKernelGGL((gemm128<0>), dim3(8, 32, 2), dim3(256), 0, stream, act, wbf_down,
                     (void*)down_parts, (const unsigned short*)nullptr, 2048, 4096, 4096, 1024,
                     2048LL, 2048LL, 4194304LL);
  // s18: out = mh + sum(partials)
  hipLaunchKernelGGL(addn_f32_k, dim3(4096), dim3(256), 0, stream, mh, down_parts, 4194304LL, 2,
                     out, 1048576LL);
}